// Round 1
// baseline (26859.943 us; speedup 1.0000x reference)
//
#include <hip/hip_runtime.h>
#include <math.h>

// ---------------------------------------------------------------------------
// RGN round 6: barrier-free recurrence via sentinel-validated data polling.
//   - h1/h2 prefilled with 0xFFFF (f16 NaN, impossible LSTM output). Producers
//     fire relaxed agent-scope u64 stores; consumers optimistically load+MFMA
//     and verify each u64 != ~0ull (u64 stores are single-copy atomic -> no
//     tearing). On miss: cheap 25-word probe spin, then full redo.
//   - No grid barrier, no flags, no __syncthreads in the step loop.
//   - Unit-major row mapping (row = u*4+g): MFMA D-layout gives each lane all
//     4 gates of one hidden unit -> lane-local epilogue, no cross-wave reduce.
//   - Per-wave full-K uniform unrolled loops (no runtime guards) -> loads
//     batch-issue. Weights stay register-resident.
//   rnn0: 50 blocks (25/dir), wave = 8 units (mt=2), K = 2 x-tiles + 25 h-tiles
//   rnn1: 100 blocks (50/dir), wave = 4 units (mt=1), K = 50 h1 + 25 h2 tiles
// ---------------------------------------------------------------------------

#define TT 512
#define BB 32
#define HH 800
#define DIN 41
#define XPAD 64
#define KROW 1600

typedef _Float16 f16;
typedef _Float16 half8 __attribute__((ext_vector_type(8)));
typedef float floatx4 __attribute__((ext_vector_type(4)));
typedef unsigned uint4v __attribute__((ext_vector_type(4)));

// ---------------- workspace layout (float-slot offsets) --------------------
#define OFF_XT   8192                       // f16 [512][32][64]
#define OFF_H1   (OFF_XT + 524288)          // f16 [512][32][1600]
#define OFF_H2   (OFF_H1 + 13107200)        // f16 [512][32][1600]
#define OFF_ANG  (OFF_H2 + 13107200)        // f32 [512][32][3]
#define OFF_SIN  (OFF_ANG + 49152)
#define OFF_COS  (OFF_SIN + 64)

#define SENT 0xFFFFFFFFFFFFFFFFull

__device__ __forceinline__ float sigm(float x) { return 1.0f / (1.0f + expf(-x)); }

union U64H8 { unsigned long long u[2]; half8 h; };

__device__ __forceinline__ unsigned long long ald8(const f16* p) {
    return __hip_atomic_load((const unsigned long long*)p, __ATOMIC_RELAXED, __HIP_MEMORY_SCOPE_AGENT);
}
__device__ __forceinline__ void ast8(f16* p, unsigned long long v) {
    __hip_atomic_store((unsigned long long*)p, v, __ATOMIC_RELAXED, __HIP_MEMORY_SCOPE_AGENT);
}
__device__ __forceinline__ half8 cvt8(const float* p) {
    half8 r;
#pragma unroll
    for (int i = 0; i < 8; ++i) r[i] = (f16)p[i];
    return r;
}

// ===========================================================================
// rnn0: layer 0. 25 blocks/dir. wave = 8 units (mt=2). K = 64(x) + 800(h).
// ===========================================================================
__global__ __launch_bounds__(256, 1) void rnn0_kernel(
    const f16* __restrict__ xT, f16* __restrict__ h1,
    const float* __restrict__ Wih_f0, const float* __restrict__ Whh_f0, const float* __restrict__ b_f0,
    const float* __restrict__ Wih_b0, const float* __restrict__ Whh_b0, const float* __restrict__ b_b0)
{
    __shared__ f16 sh[4][32][8];
    const int tid  = threadIdx.x;
    const int w    = tid >> 6;
    const int lane = tid & 63;
    const int l15  = lane & 15;
    const int quad = lane >> 4;
    const int dir  = blockIdx.x / 25;
    const int blk  = blockIdx.x % 25;
    const int j0w  = (blk * 4 + w) * 8;          // first of this wave's 8 units

    const float* Wih = dir ? Wih_b0 : Wih_f0;
    const float* Whh = dir ? Whh_b0 : Whh_f0;
    const float* bs  = dir ? b_b0  : b_f0;

    // A fragments, unit-major rows: m = u*4 + g  (u = m>>2, g = m&3)
    half8 afr[2][27];
#pragma unroll
    for (int mt = 0; mt < 2; ++mt) {
        const int grow = (l15 & 3) * HH + j0w + mt * 4 + (l15 >> 2);
#pragma unroll
        for (int kt = 0; kt < 27; ++kt) {
            half8 v;
#pragma unroll
            for (int jj = 0; jj < 8; ++jj) v[jj] = (f16)0.f;
            if (kt < 2) {
#pragma unroll
                for (int jj = 0; jj < 8; ++jj) {
                    const int k = kt * 32 + quad * 8 + jj;
                    if (k < DIN) v[jj] = (f16)Wih[(size_t)grow * DIN + k];
                }
            } else {
                v = cvt8(Whh + (size_t)grow * HH + (kt - 2) * 32 + quad * 8);
            }
            afr[mt][kt] = v;
        }
    }
    float bias[2][4];
#pragma unroll
    for (int mt = 0; mt < 2; ++mt)
#pragma unroll
        for (int g = 0; g < 4; ++g)
            bias[mt][g] = bs[g * HH + j0w + mt * 4 + quad];

    float c[2][2] = {{0.f, 0.f}, {0.f, 0.f}};

    for (int s = 0; s < TT; ++s) {
        const int t = dir ? (TT - 1 - s) : s;

        // ---- static x part ----
        floatx4 accx[2][2];
        accx[0][0] = (floatx4)0.f; accx[0][1] = (floatx4)0.f;
        accx[1][0] = (floatx4)0.f; accx[1][1] = (floatx4)0.f;
        const f16* xrow = xT + (size_t)t * BB * XPAD + quad * 8;
#pragma unroll
        for (int kt = 0; kt < 2; ++kt) {
            const half8 b0 = *(const half8*)(xrow + (size_t)l15 * XPAD + kt * 32);
            const half8 b1 = *(const half8*)(xrow + (size_t)(16 + l15) * XPAD + kt * 32);
            accx[0][0] = __builtin_amdgcn_mfma_f32_16x16x32_f16(afr[0][kt], b0, accx[0][0], 0, 0, 0);
            accx[0][1] = __builtin_amdgcn_mfma_f32_16x16x32_f16(afr[0][kt], b1, accx[0][1], 0, 0, 0);
            accx[1][0] = __builtin_amdgcn_mfma_f32_16x16x32_f16(afr[1][kt], b0, accx[1][0], 0, 0, 0);
            accx[1][1] = __builtin_amdgcn_mfma_f32_16x16x32_f16(afr[1][kt], b1, accx[1][1], 0, 0, 0);
        }

        // ---- recurrent part: optimistic consume + verify ----
        floatx4 acc[2][2];
        if (s > 0) {
            const int tp = dir ? t + 1 : t - 1;
            const f16* p0 = h1 + (size_t)tp * BB * KROW + dir * HH + quad * 8 + (size_t)l15 * KROW;
            const f16* p1 = p0 + (size_t)16 * KROW;
            int anybad;
            do {
                int bad = 0;
                acc[0][0] = accx[0][0]; acc[0][1] = accx[0][1];
                acc[1][0] = accx[1][0]; acc[1][1] = accx[1][1];
#pragma unroll
                for (int kt = 0; kt < 25; ++kt) {
                    U64H8 x0, x1;
                    x0.u[0] = ald8(p0 + kt * 32);
                    x0.u[1] = ald8(p0 + kt * 32 + 4);
                    x1.u[0] = ald8(p1 + kt * 32);
                    x1.u[1] = ald8(p1 + kt * 32 + 4);
                    bad |= (x0.u[0] == SENT) | (x0.u[1] == SENT) | (x1.u[0] == SENT) | (x1.u[1] == SENT);
                    acc[0][0] = __builtin_amdgcn_mfma_f32_16x16x32_f16(afr[0][kt + 2], x0.h, acc[0][0], 0, 0, 0);
                    acc[0][1] = __builtin_amdgcn_mfma_f32_16x16x32_f16(afr[0][kt + 2], x1.h, acc[0][1], 0, 0, 0);
                    acc[1][0] = __builtin_amdgcn_mfma_f32_16x16x32_f16(afr[1][kt + 2], x0.h, acc[1][0], 0, 0, 0);
                    acc[1][1] = __builtin_amdgcn_mfma_f32_16x16x32_f16(afr[1][kt + 2], x1.h, acc[1][1], 0, 0, 0);
                }
                anybad = __any(bad);
                if (anybad) {
                    // cheap probe spin until producers land, then full redo
                    int pb;
                    do {
                        __builtin_amdgcn_s_sleep(8);
                        pb = 0;
#pragma unroll
                        for (int kt = 0; kt < 25; ++kt)
                            pb |= (ald8(p0 + kt * 32) == SENT);
                        pb = __any(pb);
                    } while (pb);
                }
            } while (anybad);
        } else {
            acc[0][0] = accx[0][0]; acc[0][1] = accx[0][1];
            acc[1][0] = accx[1][0]; acc[1][1] = accx[1][1];
        }

        // ---- lane-local epilogue: acc[mt][nt][g] = gate g of unit (mt*4+quad)
#pragma unroll
        for (int mt = 0; mt < 2; ++mt)
#pragma unroll
            for (int nt = 0; nt < 2; ++nt) {
                const float gi = acc[mt][nt][0] + bias[mt][0];
                const float gf = acc[mt][nt][1] + bias[mt][1];
                const float gg = acc[mt][nt][2] + bias[mt][2];
                const float go = acc[mt][nt][3] + bias[mt][3];
                const float cn = sigm(gf) * c[mt][nt] + sigm(gi) * tanhf(gg);
                c[mt][nt] = cn;
                sh[w][nt * 16 + l15][mt * 4 + quad] = (f16)(sigm(go) * tanhf(cn));
            }
        __builtin_amdgcn_wave_barrier();
        {
            const int b = lane & 31, ub = lane >> 5;
            const unsigned long long hv = *(const unsigned long long*)&sh[w][b][ub * 4];
            ast8(h1 + ((size_t)t * BB + b) * KROW + dir * HH + j0w + ub * 4, hv);
        }
        __builtin_amdgcn_wave_barrier();
    }
}

// ===========================================================================
// rnn1: layer 1. 50 blocks/dir. wave = 4 units (mt=1). K = 1600(h1) + 800(h2).
// ===========================================================================
__global__ __launch_bounds__(256, 1) void rnn1_kernel(
    const f16* __restrict__ h1, f16* __restrict__ h2,
    const float* __restrict__ Wih_f1, const float* __restrict__ Whh_f1, const float* __restrict__ b_f1,
    const float* __restrict__ Wih_b1, const float* __restrict__ Whh_b1, const float* __restrict__ b_b1)
{
    __shared__ f16 sh[4][32][4];
    const int tid  = threadIdx.x;
    const int w    = tid >> 6;
    const int lane = tid & 63;
    const int l15  = lane & 15;
    const int quad = lane >> 4;
    const int dir  = blockIdx.x / 50;
    const int blk  = blockIdx.x % 50;
    const int j0w  = (blk * 4 + w) * 4;          // this wave's 4 units

    const float* Wih = dir ? Wih_b1 : Wih_f1;
    const float* Whh = dir ? Whh_b1 : Whh_f1;
    const float* bs  = dir ? b_b1  : b_f1;

    const int grow = (l15 & 3) * HH + j0w + (l15 >> 2);
    half8 afr[75];
#pragma unroll
    for (int kt = 0; kt < 75; ++kt)
        afr[kt] = (kt < 50) ? cvt8(Wih + (size_t)grow * KROW + kt * 32 + quad * 8)
                            : cvt8(Whh + (size_t)grow * HH + (kt - 50) * 32 + quad * 8);
    float bias[4];
#pragma unroll
    for (int g = 0; g < 4; ++g) bias[g] = bs[g * HH + j0w + quad];

    float c[2] = {0.f, 0.f};

    for (int s = 0; s < TT; ++s) {
        const int t = dir ? (TT - 1 - s) : s;

        // ---- static h1 part (plain cached loads; fills the wait window) ----
        floatx4 accx[2];
        accx[0] = (floatx4)0.f; accx[1] = (floatx4)0.f;
        const f16* h1row = h1 + (size_t)t * BB * KROW + quad * 8;
#pragma unroll
        for (int kt = 0; kt < 50; ++kt) {
            const half8 b0 = *(const half8*)(h1row + (size_t)l15 * KROW + kt * 32);
            const half8 b1 = *(const half8*)(h1row + (size_t)(16 + l15) * KROW + kt * 32);
            accx[0] = __builtin_amdgcn_mfma_f32_16x16x32_f16(afr[kt], b0, accx[0], 0, 0, 0);
            accx[1] = __builtin_amdgcn_mfma_f32_16x16x32_f16(afr[kt], b1, accx[1], 0, 0, 0);
        }

        // ---- recurrent h2 part ----
        floatx4 acc[2];
        if (s > 0) {
            const int tp = dir ? t + 1 : t - 1;
            const f16* p0 = h2 + (size_t)tp * BB * KROW + dir * HH + quad * 8 + (size_t)l15 * KROW;
            const f16* p1 = p0 + (size_t)16 * KROW;
            int anybad;
            do {
                int bad = 0;
                acc[0] = accx[0]; acc[1] = accx[1];
#pragma unroll
                for (int kt = 0; kt < 25; ++kt) {
                    U64H8 x0, x1;
                    x0.u[0] = ald8(p0 + kt * 32);
                    x0.u[1] = ald8(p0 + kt * 32 + 4);
                    x1.u[0] = ald8(p1 + kt * 32);
                    x1.u[1] = ald8(p1 + kt * 32 + 4);
                    bad |= (x0.u[0] == SENT) | (x0.u[1] == SENT) | (x1.u[0] == SENT) | (x1.u[1] == SENT);
                    acc[0] = __builtin_amdgcn_mfma_f32_16x16x32_f16(afr[kt + 50], x0.h, acc[0], 0, 0, 0);
                    acc[1] = __builtin_amdgcn_mfma_f32_16x16x32_f16(afr[kt + 50], x1.h, acc[1], 0, 0, 0);
                }
                anybad = __any(bad);
                if (anybad) {
                    int pb;
                    do {
                        __builtin_amdgcn_s_sleep(8);
                        pb = 0;
#pragma unroll
                        for (int kt = 0; kt < 25; ++kt)
                            pb |= (ald8(p0 + kt * 32) == SENT);
                        pb = __any(pb);
                    } while (pb);
                }
            } while (anybad);
        } else {
            acc[0] = accx[0]; acc[1] = accx[1];
        }

        // ---- lane-local epilogue ----
#pragma unroll
        for (int nt = 0; nt < 2; ++nt) {
            const float gi = acc[nt][0] + bias[0];
            const float gf = acc[nt][1] + bias[1];
            const float gg = acc[nt][2] + bias[2];
            const float go = acc[nt][3] + bias[3];
            const float cn = sigm(gf) * c[nt] + sigm(gi) * tanhf(gg);
            c[nt] = cn;
            sh[w][nt * 16 + l15][quad] = (f16)(sigm(go) * tanhf(cn));
        }
        __builtin_amdgcn_wave_barrier();
        if (lane < 32) {
            const unsigned long long hv = *(const unsigned long long*)&sh[w][lane][0];
            ast8(h2 + ((size_t)t * BB + lane) * KROW + dir * HH + j0w, hv);
        }
        __builtin_amdgcn_wave_barrier();
    }
}

// ---------------------------------------------------------------------------
// prep: xT f16 zero-padded, sin/cos tables, sentinel-fill h1+h2 (105 MB)
__global__ void prep_kernel(const float* __restrict__ x, const float* __restrict__ alphabet,
                            f16* __restrict__ xT, float* __restrict__ sin_t,
                            float* __restrict__ cos_t, unsigned* __restrict__ hsent) {
    const int gid = blockIdx.x * blockDim.x + threadIdx.x;
    const int nth = gridDim.x * blockDim.x;
    for (int idx = gid; idx < TT * BB * XPAD; idx += nth) {
        const int tb = idx >> 6;
        const int i  = idx & 63;
        xT[idx] = (i < DIN) ? (f16)x[(size_t)tb * DIN + i] : (f16)0.f;
    }
    uint4v* hs4 = (uint4v*)hsent;
    const uint4v sv = {0xFFFFFFFFu, 0xFFFFFFFFu, 0xFFFFFFFFu, 0xFFFFFFFFu};
    const int n4 = (2 * 13107200) / 4;
    for (int idx = gid; idx < n4; idx += nth) hs4[idx] = sv;
    if (gid < 60) { sin_t[gid] = sinf(alphabet[gid]); cos_t[gid] = cosf(alphabet[gid]); }
}

// logits -> softmax -> dihedral angles (h2 f16, [t][b][k])
__global__ __launch_bounds__(640, 1) void head_kernel(
    const f16* __restrict__ h2, const float* __restrict__ Wl, const float* __restrict__ bl,
    const float* __restrict__ sin_t, const float* __restrict__ cos_t,
    float* __restrict__ angles) {
    __shared__ float pl[20][33];
    __shared__ float mx[32];
    const int t = blockIdx.x;
    const int a = threadIdx.x / 32;
    const int b = threadIdx.x & 31;
    if (a < 20) {
        float acc = bl[a];
        const float* wr = Wl + (size_t)a * KROW;
        const f16*   hr = h2 + ((size_t)t * BB + b) * KROW;
        for (int k8 = 0; k8 < KROW / 8; ++k8) {
            const half8 hv = *(const half8*)(hr + k8 * 8);
#pragma unroll
            for (int j = 0; j < 8; ++j) acc = fmaf(wr[k8 * 8 + j], (float)hv[j], acc);
        }
        pl[a][b] = acc;
    }
    __syncthreads();
    if (threadIdx.x < 32) {
        float m = pl[0][threadIdx.x];
        for (int i = 1; i < 20; ++i) m = fmaxf(m, pl[i][threadIdx.x]);
        mx[threadIdx.x] = m;
    }
    __syncthreads();
    if (a < 20) pl[a][b] = expf(pl[a][b] - mx[b]);
    __syncthreads();
    if (threadIdx.x < 96) {
        const int c = threadIdx.x / 32, b2 = threadIdx.x & 31;
        float y = 0.f, xx = 0.f;
        for (int i = 0; i < 20; ++i) {
            const float e = pl[i][b2];
            y  = fmaf(e, sin_t[i * 3 + c], y);
            xx = fmaf(e, cos_t[i * 3 + c], xx);
        }
        angles[((size_t)t * BB + b2) * 3 + c] = atan2f(y, xx);
    }
}

// sequential NeRF coordinate extension, one lane per batch element
__global__ void coords_kernel(const float* __restrict__ angles, float* __restrict__ out) {
    const int b = threadIdx.x;
    if (b >= BB) return;
    const float rs[3]  = {1.458f, 1.525f, 1.33f};
    const float ths[3] = {2.124f, 1.941f, 2.028f};
    float ct[3], st[3];
#pragma unroll
    for (int k = 0; k < 3; ++k) { ct[k] = cosf(ths[k]); st[k] = sinf(ths[k]); }
    float pax = 0.f,     pay = 0.f, paz = 0.f;
    float pbx = 1.458f,  pby = 0.f, pbz = 0.f;
    float pcx = 2.f,     pcy = 1.f, pcz = 0.f;
    for (int n = 0; n < 3 * TT; ++n) {
        const int t = n / 3;
        const int k = n - 3 * t;
        const float phi = angles[((size_t)t * BB + b) * 3 + k];
        float ux = pcx - pbx, uy = pcy - pby, uz = pcz - pbz;
        const float il = rsqrtf(ux * ux + uy * uy + uz * uz);
        const float bcx = ux * il, bcy = uy * il, bcz = uz * il;
        const float wx = pbx - pax, wy = pby - pay, wz = pbz - paz;
        float cx = wy * bcz - wz * bcy, cy = wz * bcx - wx * bcz, cz = wx * bcy - wy * bcx;
        const float iln = rsqrtf(cx * cx + cy * cy + cz * cz);
        const float nx = cx * iln, ny = cy * iln, nz = cz * iln;
        const float mxv = ny * bcz - nz * bcy, myv = nz * bcx - nx * bcz, mzv = nx * bcy - ny * bcx;
        float sp, cp;
        __sincosf(phi, &sp, &cp);
        const float rr = rs[k], cth = ct[k], sth = st[k];
        const float dx = pcx - rr * cth * bcx + rr * sth * (cp * mxv + sp * nx);
        const float dy = pcy - rr * cth * bcy + rr * sth * (cp * myv + sp * ny);
        const float dz = pcz - rr * cth * bcz + rr * sth * (cp * mzv + sp * nz);
        float* o = out + ((size_t)n * BB + b) * 3;
        o[0] = dx; o[1] = dy; o[2] = dz;
        pax = pbx; pay = pby; paz = pbz;
        pbx = pcx; pby = pcy; pbz = pcz;
        pcx = dx;  pcy = dy;  pcz = dz;
    }
}

// ---------------------------------------------------------------------------
extern "C" void kernel_launch(void* const* d_in, const int* in_sizes, int n_in,
                              void* d_out, int out_size, void* d_ws, size_t ws_size,
                              hipStream_t stream) {
    (void)in_sizes; (void)n_in; (void)out_size; (void)ws_size;
    const float* x      = (const float*)d_in[0];
    const float* Wih_f0 = (const float*)d_in[1];
    const float* Whh_f0 = (const float*)d_in[2];
    const float* b_f0   = (const float*)d_in[3];
    const float* Wih_b0 = (const float*)d_in[4];
    const float* Whh_b0 = (const float*)d_in[5];
    const float* b_b0   = (const float*)d_in[6];
    const float* Wih_f1 = (const float*)d_in[7];
    const float* Whh_f1 = (const float*)d_in[8];
    const float* b_f1   = (const float*)d_in[9];
    const float* Wih_b1 = (const float*)d_in[10];
    const float* Whh_b1 = (const float*)d_in[11];
    const float* b_b1   = (const float*)d_in[12];
    const float* Wl     = (const float*)d_in[13];
    const float* bl     = (const float*)d_in[14];
    const float* alphabet = (const float*)d_in[15];

    float* ws = (float*)d_ws;
    f16*   xT     = (f16*)(ws + OFF_XT);
    f16*   h1     = (f16*)(ws + OFF_H1);
    f16*   h2     = (f16*)(ws + OFF_H2);
    float* angles = ws + OFF_ANG;
    float* sin_t  = ws + OFF_SIN;
    float* cos_t  = ws + OFF_COS;

    prep_kernel<<<1024, 256, 0, stream>>>(x, alphabet, xT, sin_t, cos_t, (unsigned*)(ws + OFF_H1));
    rnn0_kernel<<<50, 256, 0, stream>>>(xT, h1,
        Wih_f0, Whh_f0, b_f0, Wih_b0, Whh_b0, b_b0);
    rnn1_kernel<<<100, 256, 0, stream>>>(h1, h2,
        Wih_f1, Whh_f1, b_f1, Wih_b1, Whh_b1, b_b1);
    head_kernel<<<TT, 640, 0, stream>>>(h2, Wl, bl, sin_t, cos_t, angles);
    coords_kernel<<<1, 64, 0, stream>>>(angles, (float*)d_out);
}

// Round 2
// 10306.055 us; speedup vs baseline: 2.6062x; 2.6062x over previous
//
#include <hip/hip_runtime.h>
#include <math.h>

// ---------------------------------------------------------------------------
// RGN round 7: R5 geometry (200 blocks, split-K across waves, max MLP) +
// R6's sentinel polling, restructured so the probe IS the data read.
//   - h1/h2 sentinel-filled with 0xFFFF (f16 NaN, impossible LSTM output).
//   - Producers: relaxed agent-scope (LLC write-through) u64 stores, no
//     drain, no flags, no grid barrier.
//   - Consumers: per-wave retry loop loads exactly the u64s this wave will
//     MFMA (24-28, all issued back-to-back -> one overlapped LLC latency),
//     checks sentinels; on clean exit the operands are already in registers.
//   - K-tiles strided across waves (kt = w + 4*i) so bypass tiles balance
//     6-7 per wave in both kernels.
//   - 3 __syncthreads/step (gbuf/hbuf protection), all intra-block.
// ---------------------------------------------------------------------------

#define TT 512
#define BB 32
#define HH 800
#define DIN 41
#define XPAD 64
#define KROW 1600

typedef _Float16 f16;
typedef _Float16 half8 __attribute__((ext_vector_type(8)));
typedef float floatx4 __attribute__((ext_vector_type(4)));
typedef unsigned uint4v __attribute__((ext_vector_type(4)));

// ---------------- workspace layout (float-slot offsets) --------------------
#define OFF_XT   8192                       // f16 [512][32][64]
#define OFF_H1   (OFF_XT + 524288)          // f16 [512][32][1600]
#define OFF_H2   (OFF_H1 + 13107200)        // f16 [512][32][1600]
#define OFF_ANG  (OFF_H2 + 13107200)        // f32 [512][32][3]
#define OFF_SIN  (OFF_ANG + 49152)
#define OFF_COS  (OFF_SIN + 64)

#define SENT 0xFFFFFFFFFFFFFFFFull

__device__ __forceinline__ float sigm(float x) { return 1.0f / (1.0f + expf(-x)); }

union U64H8 { unsigned long long u[2]; half8 h; };

__device__ __forceinline__ unsigned long long ald8(const f16* p) {
    return __hip_atomic_load((const unsigned long long*)p, __ATOMIC_RELAXED, __HIP_MEMORY_SCOPE_AGENT);
}
__device__ __forceinline__ void ast8(f16* p, unsigned long long v) {
    __hip_atomic_store((unsigned long long*)p, v, __ATOMIC_RELAXED, __HIP_MEMORY_SCOPE_AGENT);
}
__device__ __forceinline__ half8 cvt8(const float* p) {
    half8 r;
#pragma unroll
    for (int i = 0; i < 8; ++i) r[i] = (f16)p[i];
    return r;
}

// ===========================================================================
// rnn0: layer 0. 100 blocks/dir, 8 units/block. K = 64(x) + 800(h_prev),
// 27 k-tiles strided across 4 waves (kt = w + 4*i, i<7).
// ===========================================================================
__global__ __launch_bounds__(256, 1) void rnn0_kernel(
    const f16* __restrict__ xT, f16* __restrict__ h1,
    const float* __restrict__ Wih_f0, const float* __restrict__ Whh_f0, const float* __restrict__ b_f0,
    const float* __restrict__ Wih_b0, const float* __restrict__ Whh_b0, const float* __restrict__ b_b0)
{
    __shared__ float gbuf[4][32][33];
    __shared__ f16  hbuf[256];

    const int tid  = threadIdx.x;
    const int w    = tid >> 6;
    const int lane = tid & 63;
    const int l15  = lane & 15;
    const int quad = lane >> 4;
    const int dir  = blockIdx.x / 100;
    const int blk  = blockIdx.x % 100;
    const int j0   = blk * 8;
    const int jl   = tid >> 5;          // epilogue: hidden unit 0..7
    const int bb   = tid & 31;          // epilogue: batch

    const float* Wih = dir ? Wih_b0 : Wih_f0;
    const float* Whh = dir ? Whh_b0 : Whh_f0;
    const float* bs  = dir ? b_b0  : b_f0;

    // A-fragments: rows gate-major (r>>3 = gate, r&7 = unit), k strided by wave
    half8 afr[2][7];
#pragma unroll
    for (int mt = 0; mt < 2; ++mt) {
        const int r = mt * 16 + l15;
        const int grow = (r >> 3) * HH + j0 + (r & 7);
#pragma unroll
        for (int i = 0; i < 7; ++i) {
            const int kt = w + 4 * i;
            half8 v;
#pragma unroll
            for (int jj = 0; jj < 8; ++jj) v[jj] = (f16)0.f;
            if (kt < 27) {
                if (kt < 2) {
#pragma unroll
                    for (int jj = 0; jj < 8; ++jj) {
                        const int k = kt * 32 + quad * 8 + jj;
                        if (k < DIN) v[jj] = (f16)Wih[(size_t)grow * DIN + k];
                    }
                } else {
                    v = cvt8(Whh + (size_t)grow * HH + (kt - 2) * 32 + quad * 8);
                }
            }
            afr[mt][i] = v;
        }
    }
    const float bi = bs[0 * HH + j0 + jl], bf = bs[1 * HH + j0 + jl],
                bg = bs[2 * HH + j0 + jl], bo = bs[3 * HH + j0 + jl];

    float creg = 0.0f;
    for (int s = 0; s < TT; ++s) {
        const int t  = dir ? (TT - 1 - s) : s;
        const int tp = dir ? t + 1 : t - 1;
        floatx4 acc[2][2];
        acc[0][0] = (floatx4)0.f; acc[0][1] = (floatx4)0.f;
        acc[1][0] = (floatx4)0.f; acc[1][1] = (floatx4)0.f;

        // ---- phase A: static x tiles (cached) ----
        const f16* xrow = xT + (size_t)t * BB * XPAD + quad * 8;
#pragma unroll
        for (int i = 0; i < 7; ++i) {
            const int kt = w + 4 * i;
            if (kt < 2) {
                const f16* p = xrow + kt * 32;
                const half8 b0 = *(const half8*)(p + (size_t)l15 * XPAD);
                const half8 b1 = *(const half8*)(p + (size_t)(16 + l15) * XPAD);
                acc[0][0] = __builtin_amdgcn_mfma_f32_16x16x32_f16(afr[0][i], b0, acc[0][0], 0, 0, 0);
                acc[0][1] = __builtin_amdgcn_mfma_f32_16x16x32_f16(afr[0][i], b1, acc[0][1], 0, 0, 0);
                acc[1][0] = __builtin_amdgcn_mfma_f32_16x16x32_f16(afr[1][i], b0, acc[1][0], 0, 0, 0);
                acc[1][1] = __builtin_amdgcn_mfma_f32_16x16x32_f16(afr[1][i], b1, acc[1][1], 0, 0, 0);
            }
        }

        // ---- phase B: recurrent h tiles; probe loop IS the read ----
        if (s > 0) {
            const f16* hrow = h1 + (size_t)tp * BB * KROW + dir * HH + quad * 8;
            U64H8 rb[7][2];
            for (;;) {
                int bad = 0;
#pragma unroll
                for (int i = 0; i < 7; ++i) {
                    const int kt = w + 4 * i;
                    if (kt >= 2 && kt < 27) {
                        const f16* p = hrow + (kt - 2) * 32;
                        rb[i][0].u[0] = ald8(p + (size_t)l15 * KROW);
                        rb[i][0].u[1] = ald8(p + (size_t)l15 * KROW + 4);
                        rb[i][1].u[0] = ald8(p + (size_t)(16 + l15) * KROW);
                        rb[i][1].u[1] = ald8(p + (size_t)(16 + l15) * KROW + 4);
                        bad |= (rb[i][0].u[0] == SENT) | (rb[i][0].u[1] == SENT) |
                               (rb[i][1].u[0] == SENT) | (rb[i][1].u[1] == SENT);
                    }
                }
                if (!__any(bad)) break;
                __builtin_amdgcn_s_sleep(1);
            }
#pragma unroll
            for (int i = 0; i < 7; ++i) {
                const int kt = w + 4 * i;
                if (kt >= 2 && kt < 27) {
                    acc[0][0] = __builtin_amdgcn_mfma_f32_16x16x32_f16(afr[0][i], rb[i][0].h, acc[0][0], 0, 0, 0);
                    acc[0][1] = __builtin_amdgcn_mfma_f32_16x16x32_f16(afr[0][i], rb[i][1].h, acc[0][1], 0, 0, 0);
                    acc[1][0] = __builtin_amdgcn_mfma_f32_16x16x32_f16(afr[1][i], rb[i][0].h, acc[1][0], 0, 0, 0);
                    acc[1][1] = __builtin_amdgcn_mfma_f32_16x16x32_f16(afr[1][i], rb[i][1].h, acc[1][1], 0, 0, 0);
                }
            }
        }

        // ---- cross-wave reduce + epilogue (R5 layout) ----
#pragma unroll
        for (int mt = 0; mt < 2; ++mt)
#pragma unroll
            for (int nt = 0; nt < 2; ++nt)
#pragma unroll
                for (int rg = 0; rg < 4; ++rg)
                    gbuf[w][mt * 16 + quad * 4 + rg][nt * 16 + l15] = acc[mt][nt][rg];
        __syncthreads();
        {
            float gi_ = bi, gf_ = bf, gc_ = bg, go_ = bo;
#pragma unroll
            for (int ww = 0; ww < 4; ++ww) {
                gi_ += gbuf[ww][jl][bb];
                gf_ += gbuf[ww][8 + jl][bb];
                gc_ += gbuf[ww][16 + jl][bb];
                go_ += gbuf[ww][24 + jl][bb];
            }
            const float cn = sigm(gf_) * creg + sigm(gi_) * tanhf(gc_);
            creg = cn;
            hbuf[bb * 8 + jl] = (f16)(sigm(go_) * tanhf(cn));
        }
        __syncthreads();
        if (tid < BB) {
            f16* dst = h1 + ((size_t)t * BB + tid) * KROW + dir * HH + j0;
            const unsigned long long* src = (const unsigned long long*)(hbuf + tid * 8);
            ast8(dst, src[0]);
            ast8(dst + 4, src[1]);
        }
        __syncthreads();
    }
}

// ===========================================================================
// rnn1: layer 1. 100 blocks/dir, 8 units/block. K = 1600(h1, cached) +
// 800(h2 prev, bypass). 75 k-tiles strided across waves (kt = w + 4*i, i<19).
// ===========================================================================
__global__ __launch_bounds__(256, 1) void rnn1_kernel(
    const f16* __restrict__ h1, f16* __restrict__ h2,
    const float* __restrict__ Wih_f1, const float* __restrict__ Whh_f1, const float* __restrict__ b_f1,
    const float* __restrict__ Wih_b1, const float* __restrict__ Whh_b1, const float* __restrict__ b_b1)
{
    __shared__ float gbuf[4][32][33];
    __shared__ f16  hbuf[256];

    const int tid  = threadIdx.x;
    const int w    = tid >> 6;
    const int lane = tid & 63;
    const int l15  = lane & 15;
    const int quad = lane >> 4;
    const int dir  = blockIdx.x / 100;
    const int blk  = blockIdx.x % 100;
    const int j0   = blk * 8;
    const int jl   = tid >> 5;
    const int bb   = tid & 31;

    const float* Wih = dir ? Wih_b1 : Wih_f1;
    const float* Whh = dir ? Whh_b1 : Whh_f1;
    const float* bs  = dir ? b_b1  : b_f1;

    half8 afr[2][19];
#pragma unroll
    for (int mt = 0; mt < 2; ++mt) {
        const int r = mt * 16 + l15;
        const int grow = (r >> 3) * HH + j0 + (r & 7);
#pragma unroll
        for (int i = 0; i < 19; ++i) {
            const int kt = w + 4 * i;
            half8 v;
#pragma unroll
            for (int jj = 0; jj < 8; ++jj) v[jj] = (f16)0.f;
            if (kt < 75) {
                if (kt < 50) v = cvt8(Wih + (size_t)grow * KROW + kt * 32 + quad * 8);
                else         v = cvt8(Whh + (size_t)grow * HH + (kt - 50) * 32 + quad * 8);
            }
            afr[mt][i] = v;
        }
    }
    const float bi = bs[0 * HH + j0 + jl], bf = bs[1 * HH + j0 + jl],
                bg = bs[2 * HH + j0 + jl], bo = bs[3 * HH + j0 + jl];

    float creg = 0.0f;
    for (int s = 0; s < TT; ++s) {
        const int t  = dir ? (TT - 1 - s) : s;
        const int tp = dir ? t + 1 : t - 1;
        floatx4 acc[2][2];
        acc[0][0] = (floatx4)0.f; acc[0][1] = (floatx4)0.f;
        acc[1][0] = (floatx4)0.f; acc[1][1] = (floatx4)0.f;

        // ---- phase A: h1[t] (static, cached) ----
        const f16* h1row = h1 + (size_t)t * BB * KROW + quad * 8;
#pragma unroll
        for (int i = 0; i < 19; ++i) {
            const int kt = w + 4 * i;
            if (kt < 50) {
                const f16* p = h1row + kt * 32;
                const half8 b0 = *(const half8*)(p + (size_t)l15 * KROW);
                const half8 b1 = *(const half8*)(p + (size_t)(16 + l15) * KROW);
                acc[0][0] = __builtin_amdgcn_mfma_f32_16x16x32_f16(afr[0][i], b0, acc[0][0], 0, 0, 0);
                acc[0][1] = __builtin_amdgcn_mfma_f32_16x16x32_f16(afr[0][i], b1, acc[0][1], 0, 0, 0);
                acc[1][0] = __builtin_amdgcn_mfma_f32_16x16x32_f16(afr[1][i], b0, acc[1][0], 0, 0, 0);
                acc[1][1] = __builtin_amdgcn_mfma_f32_16x16x32_f16(afr[1][i], b1, acc[1][1], 0, 0, 0);
            }
        }

        // ---- phase B: h2 prev (bypass), probe loop IS the read ----
        if (s > 0) {
            const f16* hrow = h2 + (size_t)tp * BB * KROW + dir * HH + quad * 8;
            U64H8 rb[7][2];
            for (;;) {
                int bad = 0;
#pragma unroll
                for (int i = 12; i < 19; ++i) {
                    const int kt = w + 4 * i;
                    if (kt >= 50 && kt < 75) {
                        const f16* p = hrow + (kt - 50) * 32;
                        rb[i - 12][0].u[0] = ald8(p + (size_t)l15 * KROW);
                        rb[i - 12][0].u[1] = ald8(p + (size_t)l15 * KROW + 4);
                        rb[i - 12][1].u[0] = ald8(p + (size_t)(16 + l15) * KROW);
                        rb[i - 12][1].u[1] = ald8(p + (size_t)(16 + l15) * KROW + 4);
                        bad |= (rb[i - 12][0].u[0] == SENT) | (rb[i - 12][0].u[1] == SENT) |
                               (rb[i - 12][1].u[0] == SENT) | (rb[i - 12][1].u[1] == SENT);
                    }
                }
                if (!__any(bad)) break;
                __builtin_amdgcn_s_sleep(1);
            }
#pragma unroll
            for (int i = 12; i < 19; ++i) {
                const int kt = w + 4 * i;
                if (kt >= 50 && kt < 75) {
                    acc[0][0] = __builtin_amdgcn_mfma_f32_16x16x32_f16(afr[0][i], rb[i - 12][0].h, acc[0][0], 0, 0, 0);
                    acc[0][1] = __builtin_amdgcn_mfma_f32_16x16x32_f16(afr[0][i], rb[i - 12][1].h, acc[0][1], 0, 0, 0);
                    acc[1][0] = __builtin_amdgcn_mfma_f32_16x16x32_f16(afr[1][i], rb[i - 12][0].h, acc[1][0], 0, 0, 0);
                    acc[1][1] = __builtin_amdgcn_mfma_f32_16x16x32_f16(afr[1][i], rb[i - 12][1].h, acc[1][1], 0, 0, 0);
                }
            }
        }

        // ---- cross-wave reduce + epilogue ----
#pragma unroll
        for (int mt = 0; mt < 2; ++mt)
#pragma unroll
            for (int nt = 0; nt < 2; ++nt)
#pragma unroll
                for (int rg = 0; rg < 4; ++rg)
                    gbuf[w][mt * 16 + quad * 4 + rg][nt * 16 + l15] = acc[mt][nt][rg];
        __syncthreads();
        {
            float gi_ = bi, gf_ = bf, gc_ = bg, go_ = bo;
#pragma unroll
            for (int ww = 0; ww < 4; ++ww) {
                gi_ += gbuf[ww][jl][bb];
                gf_ += gbuf[ww][8 + jl][bb];
                gc_ += gbuf[ww][16 + jl][bb];
                go_ += gbuf[ww][24 + jl][bb];
            }
            const float cn = sigm(gf_) * creg + sigm(gi_) * tanhf(gc_);
            creg = cn;
            hbuf[bb * 8 + jl] = (f16)(sigm(go_) * tanhf(cn));
        }
        __syncthreads();
        if (tid < BB) {
            f16* dst = h2 + ((size_t)t * BB + tid) * KROW + dir * HH + j0;
            const unsigned long long* src = (const unsigned long long*)(hbuf + tid * 8);
            ast8(dst, src[0]);
            ast8(dst + 4, src[1]);
        }
        __syncthreads();
    }
}

// ---------------------------------------------------------------------------
// prep: xT f16 zero-padded, sin/cos tables, sentinel-fill h1+h2 (105 MB)
__global__ void prep_kernel(const float* __restrict__ x, const float* __restrict__ alphabet,
                            f16* __restrict__ xT, float* __restrict__ sin_t,
                            float* __restrict__ cos_t, unsigned* __restrict__ hsent) {
    const int gid = blockIdx.x * blockDim.x + threadIdx.x;
    const int nth = gridDim.x * blockDim.x;
    for (int idx = gid; idx < TT * BB * XPAD; idx += nth) {
        const int tb = idx >> 6;
        const int i  = idx & 63;
        xT[idx] = (i < DIN) ? (f16)x[(size_t)tb * DIN + i] : (f16)0.f;
    }
    uint4v* hs4 = (uint4v*)hsent;
    const uint4v sv = {0xFFFFFFFFu, 0xFFFFFFFFu, 0xFFFFFFFFu, 0xFFFFFFFFu};
    const int n4 = (2 * 13107200) / 4;
    for (int idx = gid; idx < n4; idx += nth) hs4[idx] = sv;
    if (gid < 60) { sin_t[gid] = sinf(alphabet[gid]); cos_t[gid] = cosf(alphabet[gid]); }
}

// logits -> softmax -> dihedral angles (h2 f16, [t][b][k])
__global__ __launch_bounds__(640, 1) void head_kernel(
    const f16* __restrict__ h2, const float* __restrict__ Wl, const float* __restrict__ bl,
    const float* __restrict__ sin_t, const float* __restrict__ cos_t,
    float* __restrict__ angles) {
    __shared__ float pl[20][33];
    __shared__ float mx[32];
    const int t = blockIdx.x;
    const int a = threadIdx.x / 32;
    const int b = threadIdx.x & 31;
    if (a < 20) {
        float acc = bl[a];
        const float* wr = Wl + (size_t)a * KROW;
        const f16*   hr = h2 + ((size_t)t * BB + b) * KROW;
        for (int k8 = 0; k8 < KROW / 8; ++k8) {
            const half8 hv = *(const half8*)(hr + k8 * 8);
#pragma unroll
            for (int j = 0; j < 8; ++j) acc = fmaf(wr[k8 * 8 + j], (float)hv[j], acc);
        }
        pl[a][b] = acc;
    }
    __syncthreads();
    if (threadIdx.x < 32) {
        float m = pl[0][threadIdx.x];
        for (int i = 1; i < 20; ++i) m = fmaxf(m, pl[i][threadIdx.x]);
        mx[threadIdx.x] = m;
    }
    __syncthreads();
    if (a < 20) pl[a][b] = expf(pl[a][b] - mx[b]);
    __syncthreads();
    if (threadIdx.x < 96) {
        const int c = threadIdx.x / 32, b2 = threadIdx.x & 31;
        float y = 0.f, xx = 0.f;
        for (int i = 0; i < 20; ++i) {
            const float e = pl[i][b2];
            y  = fmaf(e, sin_t[i * 3 + c], y);
            xx = fmaf(e, cos_t[i * 3 + c], xx);
        }
        angles[((size_t)t * BB + b2) * 3 + c] = atan2f(y, xx);
    }
}

// sequential NeRF coordinate extension, one lane per batch element
__global__ void coords_kernel(const float* __restrict__ angles, float* __restrict__ out) {
    const int b = threadIdx.x;
    if (b >= BB) return;
    const float rs[3]  = {1.458f, 1.525f, 1.33f};
    const float ths[3] = {2.124f, 1.941f, 2.028f};
    float ct[3], st[3];
#pragma unroll
    for (int k = 0; k < 3; ++k) { ct[k] = cosf(ths[k]); st[k] = sinf(ths[k]); }
    float pax = 0.f,     pay = 0.f, paz = 0.f;
    float pbx = 1.458f,  pby = 0.f, pbz = 0.f;
    float pcx = 2.f,     pcy = 1.f, pcz = 0.f;
    for (int n = 0; n < 3 * TT; ++n) {
        const int t = n / 3;
        const int k = n - 3 * t;
        const float phi = angles[((size_t)t * BB + b) * 3 + k];
        float ux = pcx - pbx, uy = pcy - pby, uz = pcz - pbz;
        const float il = rsqrtf(ux * ux + uy * uy + uz * uz);
        const float bcx = ux * il, bcy = uy * il, bcz = uz * il;
        const float wx = pbx - pax, wy = pby - pay, wz = pbz - paz;
        float cx = wy * bcz - wz * bcy, cy = wz * bcx - wx * bcz, cz = wx * bcy - wy * bcx;
        const float iln = rsqrtf(cx * cx + cy * cy + cz * cz);
        const float nx = cx * iln, ny = cy * iln, nz = cz * iln;
        const float mxv = ny * bcz - nz * bcy, myv = nz * bcx - nx * bcz, mzv = nx * bcy - ny * bcx;
        float sp, cp;
        __sincosf(phi, &sp, &cp);
        const float rr = rs[k], cth = ct[k], sth = st[k];
        const float dx = pcx - rr * cth * bcx + rr * sth * (cp * mxv + sp * nx);
        const float dy = pcy - rr * cth * bcy + rr * sth * (cp * myv + sp * ny);
        const float dz = pcz - rr * cth * bcz + rr * sth * (cp * mzv + sp * nz);
        float* o = out + ((size_t)n * BB + b) * 3;
        o[0] = dx; o[1] = dy; o[2] = dz;
        pax = pbx; pay = pby; paz = pbz;
        pbx = pcx; pby = pcy; pbz = pcz;
        pcx = dx;  pcy = dy;  pcz = dz;
    }
}

// ---------------------------------------------------------------------------
extern "C" void kernel_launch(void* const* d_in, const int* in_sizes, int n_in,
                              void* d_out, int out_size, void* d_ws, size_t ws_size,
                              hipStream_t stream) {
    (void)in_sizes; (void)n_in; (void)out_size; (void)ws_size;
    const float* x      = (const float*)d_in[0];
    const float* Wih_f0 = (const float*)d_in[1];
    const float* Whh_f0 = (const float*)d_in[2];
    const float* b_f0   = (const float*)d_in[3];
    const float* Wih_b0 = (const float*)d_in[4];
    const float* Whh_b0 = (const float*)d_in[5];
    const float* b_b0   = (const float*)d_in[6];
    const float* Wih_f1 = (const float*)d_in[7];
    const float* Whh_f1 = (const float*)d_in[8];
    const float* b_f1   = (const float*)d_in[9];
    const float* Wih_b1 = (const float*)d_in[10];
    const float* Whh_b1 = (const float*)d_in[11];
    const float* b_b1   = (const float*)d_in[12];
    const float* Wl     = (const float*)d_in[13];
    const float* bl     = (const float*)d_in[14];
    const float* alphabet = (const float*)d_in[15];

    float* ws = (float*)d_ws;
    f16*   xT     = (f16*)(ws + OFF_XT);
    f16*   h1     = (f16*)(ws + OFF_H1);
    f16*   h2     = (f16*)(ws + OFF_H2);
    float* angles = ws + OFF_ANG;
    float* sin_t  = ws + OFF_SIN;
    float* cos_t  = ws + OFF_COS;

    prep_kernel<<<1024, 256, 0, stream>>>(x, alphabet, xT, sin_t, cos_t, (unsigned*)(ws + OFF_H1));
    rnn0_kernel<<<200, 256, 0, stream>>>(xT, h1,
        Wih_f0, Whh_f0, b_f0, Wih_b0, Whh_b0, b_b0);
    rnn1_kernel<<<200, 256, 0, stream>>>(h1, h2,
        Wih_f1, Whh_f1, b_f1, Wih_b1, Whh_b1, b_b1);
    head_kernel<<<TT, 640, 0, stream>>>(h2, Wl, bl, sin_t, cos_t, angles);
    coords_kernel<<<TT == 512 ? 1 : 1, 64, 0, stream>>>(angles, (float*)d_out);
}

// Round 3
// 5594.209 us; speedup vs baseline: 4.8014x; 1.8423x over previous
//
#include <hip/hip_runtime.h>
#include <math.h>

// ---------------------------------------------------------------------------
// RGN round 8: R7 sentinel probe-is-the-read + MFMA-fragment-ordered h layout.
//   Key fix: h stored as hp[t][kt][q][b][8] (fragment order). A wave's k-tile
//   B-operand load = 1KB contiguous (was 64 scattered cache lines / 8B LLC
//   transactions per instruction). Producers write 512B contiguous per block.
//   Same register contents as R7 -> MFMA layout unchanged.
//   - h1/h2 sentinel 0xFFFF (f16 NaN, impossible LSTM output), relaxed
//     agent-scope u64 loads/stores at LLC, no fences, no flags, no barrier.
//   - 2 __syncthreads/step (3rd was redundant: sync1 lgkm-drain orders it).
// ---------------------------------------------------------------------------

#define TT 512
#define BB 32
#define HH 800
#define DIN 41
#define KROW 1600

typedef _Float16 f16;
typedef _Float16 half8 __attribute__((ext_vector_type(8)));
typedef float floatx4 __attribute__((ext_vector_type(4)));
typedef unsigned uint4v __attribute__((ext_vector_type(4)));

// ---------------- workspace layout (float-slot offsets) --------------------
// hp layout: [t][KT][q][b][8] f16; per t: 50*4*32*8 = 51200 f16 (=1600*32)
#define OFF_XT   8192                       // xp f16 [512][2][4][32][8]
#define OFF_H1   (OFF_XT + 524288)          // hp1 f16 [512][50][4][32][8]
#define OFF_H2   (OFF_H1 + 13107200)        // hp2 f16 [512][50][4][32][8]
#define OFF_ANG  (OFF_H2 + 13107200)        // f32 [512][32][3]
#define OFF_SIN  (OFF_ANG + 49152)
#define OFF_COS  (OFF_SIN + 64)

#define SENT 0xFFFFFFFFFFFFFFFFull

__device__ __forceinline__ float sigm(float x) { return 1.0f / (1.0f + expf(-x)); }

union U64H8 { unsigned long long u[2]; half8 h; };

__device__ __forceinline__ unsigned long long ald8(const f16* p) {
    return __hip_atomic_load((const unsigned long long*)p, __ATOMIC_RELAXED, __HIP_MEMORY_SCOPE_AGENT);
}
__device__ __forceinline__ void ast8(f16* p, unsigned long long v) {
    __hip_atomic_store((unsigned long long*)p, v, __ATOMIC_RELAXED, __HIP_MEMORY_SCOPE_AGENT);
}
__device__ __forceinline__ half8 cvt8(const float* p) {
    half8 r;
#pragma unroll
    for (int i = 0; i < 8; ++i) r[i] = (f16)p[i];
    return r;
}

// fragment-order index (in f16 units): hp[t][KT][q][b][0]
__device__ __forceinline__ size_t hpi(int t, int KT, int q, int b) {
    return ((((size_t)t * 50 + KT) * 4 + q) * 32 + b) * 8;
}

// ===========================================================================
// rnn0: layer 0. 100 blocks/dir, 8 units/block. 27 k-tiles strided across
// 4 waves (kt = w + 4*i). kt<2: x (cached, packed); kt>=2: h1 prev (bypass).
// ===========================================================================
__global__ __launch_bounds__(256, 1) void rnn0_kernel(
    const f16* __restrict__ xp, f16* __restrict__ h1,
    const float* __restrict__ Wih_f0, const float* __restrict__ Whh_f0, const float* __restrict__ b_f0,
    const float* __restrict__ Wih_b0, const float* __restrict__ Whh_b0, const float* __restrict__ b_b0)
{
    __shared__ float gbuf[4][32][33];
    __shared__ f16  hbuf[256];

    const int tid  = threadIdx.x;
    const int w    = tid >> 6;
    const int lane = tid & 63;
    const int l15  = lane & 15;
    const int quad = lane >> 4;
    const int dir  = blockIdx.x / 100;
    const int blk  = blockIdx.x % 100;
    const int j0   = blk * 8;
    const int jl   = tid >> 5;          // epilogue: hidden unit 0..7
    const int bb   = tid & 31;          // epilogue: batch

    const float* Wih = dir ? Wih_b0 : Wih_f0;
    const float* Whh = dir ? Whh_b0 : Whh_f0;
    const float* bs  = dir ? b_b0  : b_f0;

    // A-fragments: rows gate-major (r>>3 = gate, r&7 = unit), k strided by wave
    half8 afr[2][7];
#pragma unroll
    for (int mt = 0; mt < 2; ++mt) {
        const int r = mt * 16 + l15;
        const int grow = (r >> 3) * HH + j0 + (r & 7);
#pragma unroll
        for (int i = 0; i < 7; ++i) {
            const int kt = w + 4 * i;
            half8 v;
#pragma unroll
            for (int jj = 0; jj < 8; ++jj) v[jj] = (f16)0.f;
            if (kt < 27) {
                if (kt < 2) {
#pragma unroll
                    for (int jj = 0; jj < 8; ++jj) {
                        const int k = kt * 32 + quad * 8 + jj;
                        if (k < DIN) v[jj] = (f16)Wih[(size_t)grow * DIN + k];
                    }
                } else {
                    v = cvt8(Whh + (size_t)grow * HH + (kt - 2) * 32 + quad * 8);
                }
            }
            afr[mt][i] = v;
        }
    }
    const float bi = bs[0 * HH + j0 + jl], bf = bs[1 * HH + j0 + jl],
                bg = bs[2 * HH + j0 + jl], bo = bs[3 * HH + j0 + jl];

    // producer tile coords: global k-group = dir*800 + blk*8
    const int KT0 = dir * 25 + (blk >> 2);
    const int q0  = blk & 3;

    float creg = 0.0f;
    for (int s = 0; s < TT; ++s) {
        const int t  = dir ? (TT - 1 - s) : s;
        const int tp = dir ? t + 1 : t - 1;
        floatx4 acc[2][2];
        acc[0][0] = (floatx4)0.f; acc[0][1] = (floatx4)0.f;
        acc[1][0] = (floatx4)0.f; acc[1][1] = (floatx4)0.f;

        // ---- phase A: x tiles (packed, cached, coalesced) ----
#pragma unroll
        for (int i = 0; i < 7; ++i) {
            const int kt = w + 4 * i;
            if (kt < 2) {
                const f16* p = xp + ((((size_t)t * 2 + kt) * 4 + quad) * 32) * 8;
                const half8 b0 = *(const half8*)(p + (size_t)l15 * 8);
                const half8 b1 = *(const half8*)(p + (size_t)(16 + l15) * 8);
                acc[0][0] = __builtin_amdgcn_mfma_f32_16x16x32_f16(afr[0][i], b0, acc[0][0], 0, 0, 0);
                acc[0][1] = __builtin_amdgcn_mfma_f32_16x16x32_f16(afr[0][i], b1, acc[0][1], 0, 0, 0);
                acc[1][0] = __builtin_amdgcn_mfma_f32_16x16x32_f16(afr[1][i], b0, acc[1][0], 0, 0, 0);
                acc[1][1] = __builtin_amdgcn_mfma_f32_16x16x32_f16(afr[1][i], b1, acc[1][1], 0, 0, 0);
            }
        }

        // ---- phase B: h1 prev tiles (bypass, coalesced); probe IS the read --
        if (s > 0) {
            U64H8 rb[7][2];
            for (;;) {
                int bad = 0;
#pragma unroll
                for (int i = 0; i < 7; ++i) {
                    const int kt = w + 4 * i;
                    if (kt >= 2 && kt < 27) {
                        const f16* p = h1 + hpi(tp, dir * 25 + (kt - 2), quad, 0);
                        rb[i][0].u[0] = ald8(p + (size_t)l15 * 8);
                        rb[i][0].u[1] = ald8(p + (size_t)l15 * 8 + 4);
                        rb[i][1].u[0] = ald8(p + (size_t)(16 + l15) * 8);
                        rb[i][1].u[1] = ald8(p + (size_t)(16 + l15) * 8 + 4);
                        bad |= (rb[i][0].u[0] == SENT) | (rb[i][0].u[1] == SENT) |
                               (rb[i][1].u[0] == SENT) | (rb[i][1].u[1] == SENT);
                    }
                }
                if (!__any(bad)) break;
                __builtin_amdgcn_s_sleep(1);
            }
#pragma unroll
            for (int i = 0; i < 7; ++i) {
                const int kt = w + 4 * i;
                if (kt >= 2 && kt < 27) {
                    acc[0][0] = __builtin_amdgcn_mfma_f32_16x16x32_f16(afr[0][i], rb[i][0].h, acc[0][0], 0, 0, 0);
                    acc[0][1] = __builtin_amdgcn_mfma_f32_16x16x32_f16(afr[0][i], rb[i][1].h, acc[0][1], 0, 0, 0);
                    acc[1][0] = __builtin_amdgcn_mfma_f32_16x16x32_f16(afr[1][i], rb[i][0].h, acc[1][0], 0, 0, 0);
                    acc[1][1] = __builtin_amdgcn_mfma_f32_16x16x32_f16(afr[1][i], rb[i][1].h, acc[1][1], 0, 0, 0);
                }
            }
        }

        // ---- cross-wave reduce + epilogue ----
#pragma unroll
        for (int mt = 0; mt < 2; ++mt)
#pragma unroll
            for (int nt = 0; nt < 2; ++nt)
#pragma unroll
                for (int rg = 0; rg < 4; ++rg)
                    gbuf[w][mt * 16 + quad * 4 + rg][nt * 16 + l15] = acc[mt][nt][rg];
        __syncthreads();
        {
            float gi_ = bi, gf_ = bf, gc_ = bg, go_ = bo;
#pragma unroll
            for (int ww = 0; ww < 4; ++ww) {
                gi_ += gbuf[ww][jl][bb];
                gf_ += gbuf[ww][8 + jl][bb];
                gc_ += gbuf[ww][16 + jl][bb];
                go_ += gbuf[ww][24 + jl][bb];
            }
            const float cn = sigm(gf_) * creg + sigm(gi_) * tanhf(gc_);
            creg = cn;
            hbuf[bb * 8 + jl] = (f16)(sigm(go_) * tanhf(cn));
        }
        __syncthreads();
        if (tid < BB) {
            f16* dst = h1 + hpi(t, KT0, q0, tid);
            const unsigned long long* src = (const unsigned long long*)(hbuf + tid * 8);
            ast8(dst, src[0]);
            ast8(dst + 4, src[1]);
        }
    }
}

// ===========================================================================
// rnn1: layer 1. 100 blocks/dir, 8 units/block. 75 k-tiles strided across
// waves (kt = w + 4*i). kt<50: h1[t] (cached, packed); kt>=50: h2 prev (bypass).
// ===========================================================================
__global__ __launch_bounds__(256, 1) void rnn1_kernel(
    const f16* __restrict__ h1, f16* __restrict__ h2,
    const float* __restrict__ Wih_f1, const float* __restrict__ Whh_f1, const float* __restrict__ b_f1,
    const float* __restrict__ Wih_b1, const float* __restrict__ Whh_b1, const float* __restrict__ b_b1)
{
    __shared__ float gbuf[4][32][33];
    __shared__ f16  hbuf[256];

    const int tid  = threadIdx.x;
    const int w    = tid >> 6;
    const int lane = tid & 63;
    const int l15  = lane & 15;
    const int quad = lane >> 4;
    const int dir  = blockIdx.x / 100;
    const int blk  = blockIdx.x % 100;
    const int j0   = blk * 8;
    const int jl   = tid >> 5;
    const int bb   = tid & 31;

    const float* Wih = dir ? Wih_b1 : Wih_f1;
    const float* Whh = dir ? Whh_b1 : Whh_f1;
    const float* bs  = dir ? b_b1  : b_f1;

    half8 afr[2][19];
#pragma unroll
    for (int mt = 0; mt < 2; ++mt) {
        const int r = mt * 16 + l15;
        const int grow = (r >> 3) * HH + j0 + (r & 7);
#pragma unroll
        for (int i = 0; i < 19; ++i) {
            const int kt = w + 4 * i;
            half8 v;
#pragma unroll
            for (int jj = 0; jj < 8; ++jj) v[jj] = (f16)0.f;
            if (kt < 75) {
                if (kt < 50) v = cvt8(Wih + (size_t)grow * KROW + kt * 32 + quad * 8);
                else         v = cvt8(Whh + (size_t)grow * HH + (kt - 50) * 32 + quad * 8);
            }
            afr[mt][i] = v;
        }
    }
    const float bi = bs[0 * HH + j0 + jl], bf = bs[1 * HH + j0 + jl],
                bg = bs[2 * HH + j0 + jl], bo = bs[3 * HH + j0 + jl];

    const int KT0 = dir * 25 + (blk >> 2);
    const int q0  = blk & 3;

    float creg = 0.0f;
    for (int s = 0; s < TT; ++s) {
        const int t  = dir ? (TT - 1 - s) : s;
        const int tp = dir ? t + 1 : t - 1;
        floatx4 acc[2][2];
        acc[0][0] = (floatx4)0.f; acc[0][1] = (floatx4)0.f;
        acc[1][0] = (floatx4)0.f; acc[1][1] = (floatx4)0.f;

        // ---- phase A: h1[t] (packed, cached, coalesced) ----
#pragma unroll
        for (int i = 0; i < 13; ++i) {
            const int kt = w + 4 * i;
            if (kt < 50) {
                const f16* p = h1 + hpi(t, kt, quad, 0);
                const half8 b0 = *(const half8*)(p + (size_t)l15 * 8);
                const half8 b1 = *(const half8*)(p + (size_t)(16 + l15) * 8);
                acc[0][0] = __builtin_amdgcn_mfma_f32_16x16x32_f16(afr[0][i], b0, acc[0][0], 0, 0, 0);
                acc[0][1] = __builtin_amdgcn_mfma_f32_16x16x32_f16(afr[0][i], b1, acc[0][1], 0, 0, 0);
                acc[1][0] = __builtin_amdgcn_mfma_f32_16x16x32_f16(afr[1][i], b0, acc[1][0], 0, 0, 0);
                acc[1][1] = __builtin_amdgcn_mfma_f32_16x16x32_f16(afr[1][i], b1, acc[1][1], 0, 0, 0);
            }
        }

        // ---- phase B: h2 prev (bypass, coalesced); probe IS the read ----
        if (s > 0) {
            U64H8 rb[7][2];
            for (;;) {
                int bad = 0;
#pragma unroll
                for (int i = 12; i < 19; ++i) {
                    const int kt = w + 4 * i;
                    if (kt >= 50 && kt < 75) {
                        const f16* p = h2 + hpi(tp, dir * 25 + (kt - 50), quad, 0);
                        rb[i - 12][0].u[0] = ald8(p + (size_t)l15 * 8);
                        rb[i - 12][0].u[1] = ald8(p + (size_t)l15 * 8 + 4);
                        rb[i - 12][1].u[0] = ald8(p + (size_t)(16 + l15) * 8);
                        rb[i - 12][1].u[1] = ald8(p + (size_t)(16 + l15) * 8 + 4);
                        bad |= (rb[i - 12][0].u[0] == SENT) | (rb[i - 12][0].u[1] == SENT) |
                               (rb[i - 12][1].u[0] == SENT) | (rb[i - 12][1].u[1] == SENT);
                    }
                }
                if (!__any(bad)) break;
                __builtin_amdgcn_s_sleep(1);
            }
#pragma unroll
            for (int i = 12; i < 19; ++i) {
                const int kt = w + 4 * i;
                if (kt >= 50 && kt < 75) {
                    acc[0][0] = __builtin_amdgcn_mfma_f32_16x16x32_f16(afr[0][i], rb[i - 12][0].h, acc[0][0], 0, 0, 0);
                    acc[0][1] = __builtin_amdgcn_mfma_f32_16x16x32_f16(afr[0][i], rb[i - 12][1].h, acc[0][1], 0, 0, 0);
                    acc[1][0] = __builtin_amdgcn_mfma_f32_16x16x32_f16(afr[1][i], rb[i - 12][0].h, acc[1][0], 0, 0, 0);
                    acc[1][1] = __builtin_amdgcn_mfma_f32_16x16x32_f16(afr[1][i], rb[i - 12][1].h, acc[1][1], 0, 0, 0);
                }
            }
        }

        // ---- cross-wave reduce + epilogue ----
#pragma unroll
        for (int mt = 0; mt < 2; ++mt)
#pragma unroll
            for (int nt = 0; nt < 2; ++nt)
#pragma unroll
                for (int rg = 0; rg < 4; ++rg)
                    gbuf[w][mt * 16 + quad * 4 + rg][nt * 16 + l15] = acc[mt][nt][rg];
        __syncthreads();
        {
            float gi_ = bi, gf_ = bf, gc_ = bg, go_ = bo;
#pragma unroll
            for (int ww = 0; ww < 4; ++ww) {
                gi_ += gbuf[ww][jl][bb];
                gf_ += gbuf[ww][8 + jl][bb];
                gc_ += gbuf[ww][16 + jl][bb];
                go_ += gbuf[ww][24 + jl][bb];
            }
            const float cn = sigm(gf_) * creg + sigm(gi_) * tanhf(gc_);
            creg = cn;
            hbuf[bb * 8 + jl] = (f16)(sigm(go_) * tanhf(cn));
        }
        __syncthreads();
        if (tid < BB) {
            f16* dst = h2 + hpi(t, KT0, q0, tid);
            const unsigned long long* src = (const unsigned long long*)(hbuf + tid * 8);
            ast8(dst, src[0]);
            ast8(dst + 4, src[1]);
        }
    }
}

// ---------------------------------------------------------------------------
// prep: xp packed f16, sin/cos tables, sentinel-fill h1+h2 (105 MB)
__global__ void prep_kernel(const float* __restrict__ x, const float* __restrict__ alphabet,
                            f16* __restrict__ xp, float* __restrict__ sin_t,
                            float* __restrict__ cos_t, unsigned* __restrict__ hsent) {
    const int gid = blockIdx.x * blockDim.x + threadIdx.x;
    const int nth = gridDim.x * blockDim.x;
    for (int idx = gid; idx < TT * BB * 64; idx += nth) {
        const int tb = idx >> 6;            // t*32+b
        const int i  = idx & 63;
        const int t  = tb >> 5;
        const int b  = tb & 31;
        // packed dest: [t][i/32][(i%32)/8][b][i%8]
        const size_t di = ((((size_t)t * 2 + (i >> 5)) * 4 + ((i >> 3) & 3)) * 32 + b) * 8 + (i & 7);
        xp[di] = (i < DIN) ? (f16)x[(size_t)tb * DIN + i] : (f16)0.f;
    }
    uint4v* hs4 = (uint4v*)hsent;
    const uint4v sv = {0xFFFFFFFFu, 0xFFFFFFFFu, 0xFFFFFFFFu, 0xFFFFFFFFu};
    const int n4 = (2 * 13107200) / 4;
    for (int idx = gid; idx < n4; idx += nth) hs4[idx] = sv;
    if (gid < 60) { sin_t[gid] = sinf(alphabet[gid]); cos_t[gid] = cosf(alphabet[gid]); }
}

// logits -> softmax -> dihedral angles (h2 packed [t][KT][q][b][8])
__global__ __launch_bounds__(640, 1) void head_kernel(
    const f16* __restrict__ h2, const float* __restrict__ Wl, const float* __restrict__ bl,
    const float* __restrict__ sin_t, const float* __restrict__ cos_t,
    float* __restrict__ angles) {
    __shared__ float pl[20][33];
    __shared__ float mx[32];
    const int t = blockIdx.x;
    const int a = threadIdx.x / 32;
    const int b = threadIdx.x & 31;
    if (a < 20) {
        float acc = bl[a];
        const float* wr = Wl + (size_t)a * KROW;
        const f16*   hr = h2 + (size_t)t * 50 * 4 * 32 * 8;
        for (int k8 = 0; k8 < KROW / 8; ++k8) {
            // k-group k8 = kt*4 + q  -> contiguous 16B at [kt][q][b]
            const half8 hv = *(const half8*)(hr + (((size_t)k8) * 32 + b) * 8);
#pragma unroll
            for (int j = 0; j < 8; ++j) acc = fmaf(wr[k8 * 8 + j], (float)hv[j], acc);
        }
        pl[a][b] = acc;
    }
    __syncthreads();
    if (threadIdx.x < 32) {
        float m = pl[0][threadIdx.x];
        for (int i = 1; i < 20; ++i) m = fmaxf(m, pl[i][threadIdx.x]);
        mx[threadIdx.x] = m;
    }
    __syncthreads();
    if (a < 20) pl[a][b] = expf(pl[a][b] - mx[b]);
    __syncthreads();
    if (threadIdx.x < 96) {
        const int c = threadIdx.x / 32, b2 = threadIdx.x & 31;
        float y = 0.f, xx = 0.f;
        for (int i = 0; i < 20; ++i) {
            const float e = pl[i][b2];
            y  = fmaf(e, sin_t[i * 3 + c], y);
            xx = fmaf(e, cos_t[i * 3 + c], xx);
        }
        angles[((size_t)t * BB + b2) * 3 + c] = atan2f(y, xx);
    }
}

// sequential NeRF coordinate extension, one lane per batch element
__global__ void coords_kernel(const float* __restrict__ angles, float* __restrict__ out) {
    const int b = threadIdx.x;
    if (b >= BB) return;
    const float rs[3]  = {1.458f, 1.525f, 1.33f};
    const float ths[3] = {2.124f, 1.941f, 2.028f};
    float ct[3], st[3];
#pragma unroll
    for (int k = 0; k < 3; ++k) { ct[k] = cosf(ths[k]); st[k] = sinf(ths[k]); }
    float pax = 0.f,     pay = 0.f, paz = 0.f;
    float pbx = 1.458f,  pby = 0.f, pbz = 0.f;
    float pcx = 2.f,     pcy = 1.f, pcz = 0.f;
    for (int n = 0; n < 3 * TT; ++n) {
        const int t = n / 3;
        const int k = n - 3 * t;
        const float phi = angles[((size_t)t * BB + b) * 3 + k];
        float ux = pcx - pbx, uy = pcy - pby, uz = pcz - pbz;
        const float il = rsqrtf(ux * ux + uy * uy + uz * uz);
        const float bcx = ux * il, bcy = uy * il, bcz = uz * il;
        const float wx = pbx - pax, wy = pby - pay, wz = pbz - paz;
        float cx = wy * bcz - wz * bcy, cy = wz * bcx - wx * bcz, cz = wx * bcy - wy * bcx;
        const float iln = rsqrtf(cx * cx + cy * cy + cz * cz);
        const float nx = cx * iln, ny = cy * iln, nz = cz * iln;
        const float mxv = ny * bcz - nz * bcy, myv = nz * bcx - nx * bcz, mzv = nx * bcy - ny * bcx;
        float sp, cp;
        __sincosf(phi, &sp, &cp);
        const float rr = rs[k], cth = ct[k], sth = st[k];
        const float dx = pcx - rr * cth * bcx + rr * sth * (cp * mxv + sp * nx);
        const float dy = pcy - rr * cth * bcy + rr * sth * (cp * myv + sp * ny);
        const float dz = pcz - rr * cth * bcz + rr * sth * (cp * mzv + sp * nz);
        float* o = out + ((size_t)n * BB + b) * 3;
        o[0] = dx; o[1] = dy; o[2] = dz;
        pax = pbx; pay = pby; paz = pbz;
        pbx = pcx; pby = pcy; pbz = pcz;
        pcx = dx;  pcy = dy;  pcz = dz;
    }
}

// ---------------------------------------------------------------------------
extern "C" void kernel_launch(void* const* d_in, const int* in_sizes, int n_in,
                              void* d_out, int out_size, void* d_ws, size_t ws_size,
                              hipStream_t stream) {
    (void)in_sizes; (void)n_in; (void)out_size; (void)ws_size;
    const float* x      = (const float*)d_in[0];
    const float* Wih_f0 = (const float*)d_in[1];
    const float* Whh_f0 = (const float*)d_in[2];
    const float* b_f0   = (const float*)d_in[3];
    const float* Wih_b0 = (const float*)d_in[4];
    const float* Whh_b0 = (const float*)d_in[5];
    const float* b_b0   = (const float*)d_in[6];
    const float* Wih_f1 = (const float*)d_in[7];
    const float* Whh_f1 = (const float*)d_in[8];
    const float* b_f1   = (const float*)d_in[9];
    const float* Wih_b1 = (const float*)d_in[10];
    const float* Whh_b1 = (const float*)d_in[11];
    const float* b_b1   = (const float*)d_in[12];
    const float* Wl     = (const float*)d_in[13];
    const float* bl     = (const float*)d_in[14];
    const float* alphabet = (const float*)d_in[15];

    float* ws = (float*)d_ws;
    f16*   xp     = (f16*)(ws + OFF_XT);
    f16*   h1     = (f16*)(ws + OFF_H1);
    f16*   h2     = (f16*)(ws + OFF_H2);
    float* angles = ws + OFF_ANG;
    float* sin_t  = ws + OFF_SIN;
    float* cos_t  = ws + OFF_COS;

    prep_kernel<<<1024, 256, 0, stream>>>(x, alphabet, xp, sin_t, cos_t, (unsigned*)(ws + OFF_H1));
    rnn0_kernel<<<200, 256, 0, stream>>>(xp, h1,
        Wih_f0, Whh_f0, b_f0, Wih_b0, Whh_b0, b_b0);
    rnn1_kernel<<<200, 256, 0, stream>>>(h1, h2,
        Wih_f1, Whh_f1, b_f1, Wih_b1, Whh_b1, b_b1);
    head_kernel<<<TT, 640, 0, stream>>>(h2, Wl, bl, sin_t, cos_t, angles);
    coords_kernel<<<1, 64, 0, stream>>>(angles, (float*)d_out);
}

// Round 4
// 4948.485 us; speedup vs baseline: 5.4279x; 1.1305x over previous
//
#include <hip/hip_runtime.h>
#include <math.h>

// ---------------------------------------------------------------------------
// RGN round 9: R8 + (1) 8-wave split-K (512-thread blocks) halving per-wave
// serial work, (2) early-issued phase-B prefetch (LLC latency hides under
// phase A), (3) per-tile verify+respin (dirty tile retries only itself).
//   - h layout hp[t][KT][q][b][8] (MFMA fragment order, coalesced 1KB tile
//     reads, 512B producer writes) -- unchanged from R8.
//   - h1/h2 sentinel 0xFFFF (f16 NaN, impossible LSTM output), relaxed
//     agent-scope u64 loads/stores at LLC, no fences, no flags, no barrier.
// ---------------------------------------------------------------------------

#define TT 512
#define BB 32
#define HH 800
#define DIN 41
#define KROW 1600

typedef _Float16 f16;
typedef _Float16 half8 __attribute__((ext_vector_type(8)));
typedef float floatx4 __attribute__((ext_vector_type(4)));
typedef unsigned uint4v __attribute__((ext_vector_type(4)));

// ---------------- workspace layout (float-slot offsets) --------------------
// hp layout: [t][KT][q][b][8] f16; per t: 50*4*32*8 = 51200 f16 (=1600*32)
#define OFF_XT   8192                       // xp f16 [512][2][4][32][8]
#define OFF_H1   (OFF_XT + 524288)          // hp1 f16 [512][50][4][32][8]
#define OFF_H2   (OFF_H1 + 13107200)        // hp2 f16 [512][50][4][32][8]
#define OFF_ANG  (OFF_H2 + 13107200)        // f32 [512][32][3]
#define OFF_SIN  (OFF_ANG + 49152)
#define OFF_COS  (OFF_SIN + 64)

#define SENT 0xFFFFFFFFFFFFFFFFull

__device__ __forceinline__ float sigm(float x) { return 1.0f / (1.0f + expf(-x)); }

union U64H8 { unsigned long long u[2]; half8 h; };

__device__ __forceinline__ unsigned long long ald8(const f16* p) {
    return __hip_atomic_load((const unsigned long long*)p, __ATOMIC_RELAXED, __HIP_MEMORY_SCOPE_AGENT);
}
__device__ __forceinline__ void ast8(f16* p, unsigned long long v) {
    __hip_atomic_store((unsigned long long*)p, v, __ATOMIC_RELAXED, __HIP_MEMORY_SCOPE_AGENT);
}
__device__ __forceinline__ half8 cvt8(const float* p) {
    half8 r;
#pragma unroll
    for (int i = 0; i < 8; ++i) r[i] = (f16)p[i];
    return r;
}

// fragment-order index (in f16 units): hp[t][KT][q][b][0]
__device__ __forceinline__ size_t hpi(int t, int KT, int q, int b) {
    return ((((size_t)t * 50 + KT) * 4 + q) * 32 + b) * 8;
}

// ===========================================================================
// rnn0: layer 0. 100 blocks/dir, 8 units/block, 8 waves. 27 k-tiles strided
// kt = w + 8*i (i<4). kt<2: x (cached, packed); 2<=kt<27: h1 prev (bypass).
// ===========================================================================
__global__ __launch_bounds__(512, 1) void rnn0_kernel(
    const f16* __restrict__ xp, f16* __restrict__ h1,
    const float* __restrict__ Wih_f0, const float* __restrict__ Whh_f0, const float* __restrict__ b_f0,
    const float* __restrict__ Wih_b0, const float* __restrict__ Whh_b0, const float* __restrict__ b_b0)
{
    __shared__ float gbuf[8][32][33];
    __shared__ f16  hbuf[256];

    const int tid  = threadIdx.x;
    const int w    = tid >> 6;          // 0..7
    const int lane = tid & 63;
    const int l15  = lane & 15;
    const int quad = lane >> 4;
    const int dir  = blockIdx.x / 100;
    const int blk  = blockIdx.x % 100;
    const int j0   = blk * 8;
    const int jl   = tid >> 5;          // epilogue: hidden unit (tid<256 -> 0..7)
    const int bb   = tid & 31;          // epilogue: batch

    const float* Wih = dir ? Wih_b0 : Wih_f0;
    const float* Whh = dir ? Whh_b0 : Whh_f0;
    const float* bs  = dir ? b_b0  : b_f0;

    // A-fragments: rows gate-major (r>>3 = gate, r&7 = unit), k strided by wave
    half8 afr[2][4];
#pragma unroll
    for (int mt = 0; mt < 2; ++mt) {
        const int r = mt * 16 + l15;
        const int grow = (r >> 3) * HH + j0 + (r & 7);
#pragma unroll
        for (int i = 0; i < 4; ++i) {
            const int kt = w + 8 * i;
            half8 v;
#pragma unroll
            for (int jj = 0; jj < 8; ++jj) v[jj] = (f16)0.f;
            if (kt < 27) {
                if (kt < 2) {
#pragma unroll
                    for (int jj = 0; jj < 8; ++jj) {
                        const int k = kt * 32 + quad * 8 + jj;
                        if (k < DIN) v[jj] = (f16)Wih[(size_t)grow * DIN + k];
                    }
                } else {
                    v = cvt8(Whh + (size_t)grow * HH + (kt - 2) * 32 + quad * 8);
                }
            }
            afr[mt][i] = v;
        }
    }
    const float bi = bs[0 * HH + j0 + jl], bf = bs[1 * HH + j0 + jl],
                bg = bs[2 * HH + j0 + jl], bo = bs[3 * HH + j0 + jl];

    const int KT0 = dir * 25 + (blk >> 2);
    const int q0  = blk & 3;

    float creg = 0.0f;
    for (int s = 0; s < TT; ++s) {
        const int t  = dir ? (TT - 1 - s) : s;
        const int tp = dir ? t + 1 : t - 1;

        // ---- early prefetch of bypass tiles (hides LLC RTT under phase A) --
        U64H8 rb[4][2];
        if (s > 0) {
#pragma unroll
            for (int i = 0; i < 4; ++i) {
                const int kt = w + 8 * i;
                if (kt >= 2 && kt < 27) {
                    const f16* p = h1 + hpi(tp, dir * 25 + (kt - 2), quad, 0);
                    rb[i][0].u[0] = ald8(p + (size_t)l15 * 8);
                    rb[i][0].u[1] = ald8(p + (size_t)l15 * 8 + 4);
                    rb[i][1].u[0] = ald8(p + (size_t)(16 + l15) * 8);
                    rb[i][1].u[1] = ald8(p + (size_t)(16 + l15) * 8 + 4);
                }
            }
        }

        floatx4 acc[2][2];
        acc[0][0] = (floatx4)0.f; acc[0][1] = (floatx4)0.f;
        acc[1][0] = (floatx4)0.f; acc[1][1] = (floatx4)0.f;

        // ---- phase A: x tiles (packed, cached, coalesced; waves 0,1) ----
        if (w < 2) {
            const f16* p = xp + ((((size_t)t * 2 + w) * 4 + quad) * 32) * 8;
            const half8 b0 = *(const half8*)(p + (size_t)l15 * 8);
            const half8 b1 = *(const half8*)(p + (size_t)(16 + l15) * 8);
            acc[0][0] = __builtin_amdgcn_mfma_f32_16x16x32_f16(afr[0][0], b0, acc[0][0], 0, 0, 0);
            acc[0][1] = __builtin_amdgcn_mfma_f32_16x16x32_f16(afr[0][0], b1, acc[0][1], 0, 0, 0);
            acc[1][0] = __builtin_amdgcn_mfma_f32_16x16x32_f16(afr[1][0], b0, acc[1][0], 0, 0, 0);
            acc[1][1] = __builtin_amdgcn_mfma_f32_16x16x32_f16(afr[1][0], b1, acc[1][1], 0, 0, 0);
        }

        // ---- phase B: per-tile verify + respin + MFMA ----
        if (s > 0) {
#pragma unroll
            for (int i = 0; i < 4; ++i) {
                const int kt = w + 8 * i;
                if (kt >= 2 && kt < 27) {
                    const f16* p = h1 + hpi(tp, dir * 25 + (kt - 2), quad, 0);
                    for (;;) {
                        const int bad = (rb[i][0].u[0] == SENT) | (rb[i][0].u[1] == SENT) |
                                        (rb[i][1].u[0] == SENT) | (rb[i][1].u[1] == SENT);
                        if (!__any(bad)) break;
                        __builtin_amdgcn_s_sleep(1);
                        rb[i][0].u[0] = ald8(p + (size_t)l15 * 8);
                        rb[i][0].u[1] = ald8(p + (size_t)l15 * 8 + 4);
                        rb[i][1].u[0] = ald8(p + (size_t)(16 + l15) * 8);
                        rb[i][1].u[1] = ald8(p + (size_t)(16 + l15) * 8 + 4);
                    }
                    acc[0][0] = __builtin_amdgcn_mfma_f32_16x16x32_f16(afr[0][i], rb[i][0].h, acc[0][0], 0, 0, 0);
                    acc[0][1] = __builtin_amdgcn_mfma_f32_16x16x32_f16(afr[0][i], rb[i][1].h, acc[0][1], 0, 0, 0);
                    acc[1][0] = __builtin_amdgcn_mfma_f32_16x16x32_f16(afr[1][i], rb[i][0].h, acc[1][0], 0, 0, 0);
                    acc[1][1] = __builtin_amdgcn_mfma_f32_16x16x32_f16(afr[1][i], rb[i][1].h, acc[1][1], 0, 0, 0);
                }
            }
        }

        // ---- cross-wave reduce + epilogue ----
#pragma unroll
        for (int mt = 0; mt < 2; ++mt)
#pragma unroll
            for (int nt = 0; nt < 2; ++nt)
#pragma unroll
                for (int rg = 0; rg < 4; ++rg)
                    gbuf[w][mt * 16 + quad * 4 + rg][nt * 16 + l15] = acc[mt][nt][rg];
        __syncthreads();
        if (tid < 256) {
            float gi_ = bi, gf_ = bf, gc_ = bg, go_ = bo;
#pragma unroll
            for (int ww = 0; ww < 8; ++ww) {
                gi_ += gbuf[ww][jl][bb];
                gf_ += gbuf[ww][8 + jl][bb];
                gc_ += gbuf[ww][16 + jl][bb];
                go_ += gbuf[ww][24 + jl][bb];
            }
            const float cn = sigm(gf_) * creg + sigm(gi_) * tanhf(gc_);
            creg = cn;
            hbuf[bb * 8 + jl] = (f16)(sigm(go_) * tanhf(cn));
        }
        __syncthreads();
        if (tid < BB) {
            f16* dst = h1 + hpi(t, KT0, q0, tid);
            const unsigned long long* src = (const unsigned long long*)(hbuf + tid * 8);
            ast8(dst, src[0]);
            ast8(dst + 4, src[1]);
        }
    }
}

// ===========================================================================
// rnn1: layer 1. 100 blocks/dir, 8 units/block, 8 waves. 75 k-tiles strided
// kt = w + 8*i (i<10). kt<50: h1[t] (cached); 50<=kt<75: h2 prev (bypass).
// ===========================================================================
__global__ __launch_bounds__(512, 1) void rnn1_kernel(
    const f16* __restrict__ h1, f16* __restrict__ h2,
    const float* __restrict__ Wih_f1, const float* __restrict__ Whh_f1, const float* __restrict__ b_f1,
    const float* __restrict__ Wih_b1, const float* __restrict__ Whh_b1, const float* __restrict__ b_b1)
{
    __shared__ float gbuf[8][32][33];
    __shared__ f16  hbuf[256];

    const int tid  = threadIdx.x;
    const int w    = tid >> 6;
    const int lane = tid & 63;
    const int l15  = lane & 15;
    const int quad = lane >> 4;
    const int dir  = blockIdx.x / 100;
    const int blk  = blockIdx.x % 100;
    const int j0   = blk * 8;
    const int jl   = tid >> 5;
    const int bb   = tid & 31;

    const float* Wih = dir ? Wih_b1 : Wih_f1;
    const float* Whh = dir ? Whh_b1 : Whh_f1;
    const float* bs  = dir ? b_b1  : b_f1;

    half8 afr[2][10];
#pragma unroll
    for (int mt = 0; mt < 2; ++mt) {
        const int r = mt * 16 + l15;
        const int grow = (r >> 3) * HH + j0 + (r & 7);
#pragma unroll
        for (int i = 0; i < 10; ++i) {
            const int kt = w + 8 * i;
            half8 v;
#pragma unroll
            for (int jj = 0; jj < 8; ++jj) v[jj] = (f16)0.f;
            if (kt < 75) {
                if (kt < 50) v = cvt8(Wih + (size_t)grow * KROW + kt * 32 + quad * 8);
                else         v = cvt8(Whh + (size_t)grow * HH + (kt - 50) * 32 + quad * 8);
            }
            afr[mt][i] = v;
        }
    }
    const float bi = bs[0 * HH + j0 + jl], bf = bs[1 * HH + j0 + jl],
                bg = bs[2 * HH + j0 + jl], bo = bs[3 * HH + j0 + jl];

    const int KT0 = dir * 25 + (blk >> 2);
    const int q0  = blk & 3;

    float creg = 0.0f;
    for (int s = 0; s < TT; ++s) {
        const int t  = dir ? (TT - 1 - s) : s;
        const int tp = dir ? t + 1 : t - 1;

        // ---- early prefetch of bypass tiles ----
        U64H8 rb[10][2];
        if (s > 0) {
#pragma unroll
            for (int i = 0; i < 10; ++i) {
                const int kt = w + 8 * i;
                if (kt >= 50 && kt < 75) {
                    const f16* p = h2 + hpi(tp, dir * 25 + (kt - 50), quad, 0);
                    rb[i][0].u[0] = ald8(p + (size_t)l15 * 8);
                    rb[i][0].u[1] = ald8(p + (size_t)l15 * 8 + 4);
                    rb[i][1].u[0] = ald8(p + (size_t)(16 + l15) * 8);
                    rb[i][1].u[1] = ald8(p + (size_t)(16 + l15) * 8 + 4);
                }
            }
        }

        floatx4 acc[2][2];
        acc[0][0] = (floatx4)0.f; acc[0][1] = (floatx4)0.f;
        acc[1][0] = (floatx4)0.f; acc[1][1] = (floatx4)0.f;

        // ---- phase A: h1[t] (packed, cached, coalesced) ----
#pragma unroll
        for (int i = 0; i < 7; ++i) {
            const int kt = w + 8 * i;
            if (kt < 50) {
                const f16* p = h1 + hpi(t, kt, quad, 0);
                const half8 b0 = *(const half8*)(p + (size_t)l15 * 8);
                const half8 b1 = *(const half8*)(p + (size_t)(16 + l15) * 8);
                acc[0][0] = __builtin_amdgcn_mfma_f32_16x16x32_f16(afr[0][i], b0, acc[0][0], 0, 0, 0);
                acc[0][1] = __builtin_amdgcn_mfma_f32_16x16x32_f16(afr[0][i], b1, acc[0][1], 0, 0, 0);
                acc[1][0] = __builtin_amdgcn_mfma_f32_16x16x32_f16(afr[1][i], b0, acc[1][0], 0, 0, 0);
                acc[1][1] = __builtin_amdgcn_mfma_f32_16x16x32_f16(afr[1][i], b1, acc[1][1], 0, 0, 0);
            }
        }

        // ---- phase B: per-tile verify + respin + MFMA ----
        if (s > 0) {
#pragma unroll
            for (int i = 0; i < 10; ++i) {
                const int kt = w + 8 * i;
                if (kt >= 50 && kt < 75) {
                    const f16* p = h2 + hpi(tp, dir * 25 + (kt - 50), quad, 0);
                    for (;;) {
                        const int bad = (rb[i][0].u[0] == SENT) | (rb[i][0].u[1] == SENT) |
                                        (rb[i][1].u[0] == SENT) | (rb[i][1].u[1] == SENT);
                        if (!__any(bad)) break;
                        __builtin_amdgcn_s_sleep(1);
                        rb[i][0].u[0] = ald8(p + (size_t)l15 * 8);
                        rb[i][0].u[1] = ald8(p + (size_t)l15 * 8 + 4);
                        rb[i][1].u[0] = ald8(p + (size_t)(16 + l15) * 8);
                        rb[i][1].u[1] = ald8(p + (size_t)(16 + l15) * 8 + 4);
                    }
                    acc[0][0] = __builtin_amdgcn_mfma_f32_16x16x32_f16(afr[0][i], rb[i][0].h, acc[0][0], 0, 0, 0);
                    acc[0][1] = __builtin_amdgcn_mfma_f32_16x16x32_f16(afr[0][i], rb[i][1].h, acc[0][1], 0, 0, 0);
                    acc[1][0] = __builtin_amdgcn_mfma_f32_16x16x32_f16(afr[1][i], rb[i][0].h, acc[1][0], 0, 0, 0);
                    acc[1][1] = __builtin_amdgcn_mfma_f32_16x16x32_f16(afr[1][i], rb[i][1].h, acc[1][1], 0, 0, 0);
                }
            }
        }

        // ---- cross-wave reduce + epilogue ----
#pragma unroll
        for (int mt = 0; mt < 2; ++mt)
#pragma unroll
            for (int nt = 0; nt < 2; ++nt)
#pragma unroll
                for (int rg = 0; rg < 4; ++rg)
                    gbuf[w][mt * 16 + quad * 4 + rg][nt * 16 + l15] = acc[mt][nt][rg];
        __syncthreads();
        if (tid < 256) {
            float gi_ = bi, gf_ = bf, gc_ = bg, go_ = bo;
#pragma unroll
            for (int ww = 0; ww < 8; ++ww) {
                gi_ += gbuf[ww][jl][bb];
                gf_ += gbuf[ww][8 + jl][bb];
                gc_ += gbuf[ww][16 + jl][bb];
                go_ += gbuf[ww][24 + jl][bb];
            }
            const float cn = sigm(gf_) * creg + sigm(gi_) * tanhf(gc_);
            creg = cn;
            hbuf[bb * 8 + jl] = (f16)(sigm(go_) * tanhf(cn));
        }
        __syncthreads();
        if (tid < BB) {
            f16* dst = h2 + hpi(t, KT0, q0, tid);
            const unsigned long long* src = (const unsigned long long*)(hbuf + tid * 8);
            ast8(dst, src[0]);
            ast8(dst + 4, src[1]);
        }
    }
}

// ---------------------------------------------------------------------------
// prep: xp packed f16, sin/cos tables, sentinel-fill h1+h2 (105 MB)
__global__ void prep_kernel(const float* __restrict__ x, const float* __restrict__ alphabet,
                            f16* __restrict__ xp, float* __restrict__ sin_t,
                            float* __restrict__ cos_t, unsigned* __restrict__ hsent) {
    const int gid = blockIdx.x * blockDim.x + threadIdx.x;
    const int nth = gridDim.x * blockDim.x;
    for (int idx = gid; idx < TT * BB * 64; idx += nth) {
        const int tb = idx >> 6;            // t*32+b
        const int i  = idx & 63;
        const int t  = tb >> 5;
        const int b  = tb & 31;
        const size_t di = ((((size_t)t * 2 + (i >> 5)) * 4 + ((i >> 3) & 3)) * 32 + b) * 8 + (i & 7);
        xp[di] = (i < DIN) ? (f16)x[(size_t)tb * DIN + i] : (f16)0.f;
    }
    uint4v* hs4 = (uint4v*)hsent;
    const uint4v sv = {0xFFFFFFFFu, 0xFFFFFFFFu, 0xFFFFFFFFu, 0xFFFFFFFFu};
    const int n4 = (2 * 13107200) / 4;
    for (int idx = gid; idx < n4; idx += nth) hs4[idx] = sv;
    if (gid < 60) { sin_t[gid] = sinf(alphabet[gid]); cos_t[gid] = cosf(alphabet[gid]); }
}

// logits -> softmax -> dihedral angles (h2 packed [t][KT][q][b][8])
__global__ __launch_bounds__(640, 1) void head_kernel(
    const f16* __restrict__ h2, const float* __restrict__ Wl, const float* __restrict__ bl,
    const float* __restrict__ sin_t, const float* __restrict__ cos_t,
    float* __restrict__ angles) {
    __shared__ float pl[20][33];
    __shared__ float mx[32];
    const int t = blockIdx.x;
    const int a = threadIdx.x / 32;
    const int b = threadIdx.x & 31;
    if (a < 20) {
        float acc = bl[a];
        const float* wr = Wl + (size_t)a * KROW;
        const f16*   hr = h2 + (size_t)t * 50 * 4 * 32 * 8;
        for (int k8 = 0; k8 < KROW / 8; ++k8) {
            const half8 hv = *(const half8*)(hr + (((size_t)k8) * 32 + b) * 8);
#pragma unroll
            for (int j = 0; j < 8; ++j) acc = fmaf(wr[k8 * 8 + j], (float)hv[j], acc);
        }
        pl[a][b] = acc;
    }
    __syncthreads();
    if (threadIdx.x < 32) {
        float m = pl[0][threadIdx.x];
        for (int i = 1; i < 20; ++i) m = fmaxf(m, pl[i][threadIdx.x]);
        mx[threadIdx.x] = m;
    }
    __syncthreads();
    if (a < 20) pl[a][b] = expf(pl[a][b] - mx[b]);
    __syncthreads();
    if (threadIdx.x < 96) {
        const int c = threadIdx.x / 32, b2 = threadIdx.x & 31;
        float y = 0.f, xx = 0.f;
        for (int i = 0; i < 20; ++i) {
            const float e = pl[i][b2];
            y  = fmaf(e, sin_t[i * 3 + c], y);
            xx = fmaf(e, cos_t[i * 3 + c], xx);
        }
        angles[((size_t)t * BB + b2) * 3 + c] = atan2f(y, xx);
    }
}

// sequential NeRF coordinate extension, one lane per batch element
__global__ void coords_kernel(const float* __restrict__ angles, float* __restrict__ out) {
    const int b = threadIdx.x;
    if (b >= BB) return;
    const float rs[3]  = {1.458f, 1.525f, 1.33f};
    const float ths[3] = {2.124f, 1.941f, 2.028f};
    float ct[3], st[3];
#pragma unroll
    for (int k = 0; k < 3; ++k) { ct[k] = cosf(ths[k]); st[k] = sinf(ths[k]); }
    float pax = 0.f,     pay = 0.f, paz = 0.f;
    float pbx = 1.458f,  pby = 0.f, pbz = 0.f;
    float pcx = 2.f,     pcy = 1.f, pcz = 0.f;
    for (int n = 0; n < 3 * TT; ++n) {
        const int t = n / 3;
        const int k = n - 3 * t;
        const float phi = angles[((size_t)t * BB + b) * 3 + k];
        float ux = pcx - pbx, uy = pcy - pby, uz = pcz - pbz;
        const float il = rsqrtf(ux * ux + uy * uy + uz * uz);
        const float bcx = ux * il, bcy = uy * il, bcz = uz * il;
        const float wx = pbx - pax, wy = pby - pay, wz = pbz - paz;
        float cx = wy * bcz - wz * bcy, cy = wz * bcx - wx * bcz, cz = wx * bcy - wy * bcx;
        const float iln = rsqrtf(cx * cx + cy * cy + cz * cz);
        const float nx = cx * iln, ny = cy * iln, nz = cz * iln;
        const float mxv = ny * bcz - nz * bcy, myv = nz * bcx - nx * bcz, mzv = nx * bcy - ny * bcx;
        float sp, cp;
        __sincosf(phi, &sp, &cp);
        const float rr = rs[k], cth = ct[k], sth = st[k];
        const float dx = pcx - rr * cth * bcx + rr * sth * (cp * mxv + sp * nx);
        const float dy = pcy - rr * cth * bcy + rr * sth * (cp * myv + sp * ny);
        const float dz = pcz - rr * cth * bcz + rr * sth * (cp * mzv + sp * nz);
        float* o = out + ((size_t)n * BB + b) * 3;
        o[0] = dx; o[1] = dy; o[2] = dz;
        pax = pbx; pay = pby; paz = pbz;
        pbx = pcx; pby = pcy; pbz = pcz;
        pcx = dx;  pcy = dy;  pcz = dz;
    }
}

// ---------------------------------------------------------------------------
extern "C" void kernel_launch(void* const* d_in, const int* in_sizes, int n_in,
                              void* d_out, int out_size, void* d_ws, size_t ws_size,
                              hipStream_t stream) {
    (void)in_sizes; (void)n_in; (void)out_size; (void)ws_size;
    const float* x      = (const float*)d_in[0];
    const float* Wih_f0 = (const float*)d_in[1];
    const float* Whh_f0 = (const float*)d_in[2];
    const float* b_f0   = (const float*)d_in[3];
    const float* Wih_b0 = (const float*)d_in[4];
    const float* Whh_b0 = (const float*)d_in[5];
    const float* b_b0   = (const float*)d_in[6];
    const float* Wih_f1 = (const float*)d_in[7];
    const float* Whh_f1 = (const float*)d_in[8];
    const float* b_f1   = (const float*)d_in[9];
    const float* Wih_b1 = (const float*)d_in[10];
    const float* Whh_b1 = (const float*)d_in[11];
    const float* b_b1   = (const float*)d_in[12];
    const float* Wl     = (const float*)d_in[13];
    const float* bl     = (const float*)d_in[14];
    const float* alphabet = (const float*)d_in[15];

    float* ws = (float*)d_ws;
    f16*   xp     = (f16*)(ws + OFF_XT);
    f16*   h1     = (f16*)(ws + OFF_H1);
    f16*   h2     = (f16*)(ws + OFF_H2);
    float* angles = ws + OFF_ANG;
    float* sin_t  = ws + OFF_SIN;
    float* cos_t  = ws + OFF_COS;

    prep_kernel<<<1024, 256, 0, stream>>>(x, alphabet, xp, sin_t, cos_t, (unsigned*)(ws + OFF_H1));
    rnn0_kernel<<<200, 512, 0, stream>>>(xp, h1,
        Wih_f0, Whh_f0, b_f0, Wih_b0, Whh_b0, b_b0);
    rnn1_kernel<<<200, 512, 0, stream>>>(h1, h2,
        Wih_f1, Whh_f1, b_f1, Wih_b1, Whh_b1, b_b1);
    head_kernel<<<TT, 640, 0, stream>>>(h2, Wl, bl, sin_t, cos_t, angles);
    coords_kernel<<<1, 64, 0, stream>>>(angles, (float*)d_out);
}

// Round 5
// 4455.067 us; speedup vs baseline: 6.0291x; 1.1108x over previous
//
#include <hip/hip_runtime.h>
#include <math.h>

// ---------------------------------------------------------------------------
// RGN round 10: R9 + (1) bulk respin (re-read ALL dirty u64s per retry round,
// overlapped RTTs instead of per-tile serial spins), (2) phase-A register
// prefetch for step t+1 issued behind phase-B wait, (3) gbuf stride 34
// (2-way bank aliasing = free; stride 33 was 4-way on the partial writes).
//   - h layout hp[t][KT][q][b][8] (MFMA fragment order, coalesced 1KB tile
//     reads, 512B producer writes).
//   - h1/h2 sentinel 0xFFFF (f16 NaN, impossible LSTM output), relaxed
//     agent-scope u64 loads/stores at LLC, no fences, no flags, no barrier.
// ---------------------------------------------------------------------------

#define TT 512
#define BB 32
#define HH 800
#define DIN 41
#define KROW 1600

typedef _Float16 f16;
typedef _Float16 half8 __attribute__((ext_vector_type(8)));
typedef float floatx4 __attribute__((ext_vector_type(4)));
typedef unsigned uint4v __attribute__((ext_vector_type(4)));

// ---------------- workspace layout (float-slot offsets) --------------------
// hp layout: [t][KT][q][b][8] f16; per t: 50*4*32*8 = 51200 f16 (=1600*32)
#define OFF_XT   8192                       // xp f16 [512][2][4][32][8]
#define OFF_H1   (OFF_XT + 524288)          // hp1 f16 [512][50][4][32][8]
#define OFF_H2   (OFF_H1 + 13107200)        // hp2 f16 [512][50][4][32][8]
#define OFF_ANG  (OFF_H2 + 13107200)        // f32 [512][32][3]
#define OFF_SIN  (OFF_ANG + 49152)
#define OFF_COS  (OFF_SIN + 64)

#define SENT 0xFFFFFFFFFFFFFFFFull

__device__ __forceinline__ float sigm(float x) { return 1.0f / (1.0f + expf(-x)); }

union U64H8 { unsigned long long u[2]; half8 h; };

__device__ __forceinline__ unsigned long long ald8(const f16* p) {
    return __hip_atomic_load((const unsigned long long*)p, __ATOMIC_RELAXED, __HIP_MEMORY_SCOPE_AGENT);
}
__device__ __forceinline__ void ast8(f16* p, unsigned long long v) {
    __hip_atomic_store((unsigned long long*)p, v, __ATOMIC_RELAXED, __HIP_MEMORY_SCOPE_AGENT);
}
__device__ __forceinline__ half8 cvt8(const float* p) {
    half8 r;
#pragma unroll
    for (int i = 0; i < 8; ++i) r[i] = (f16)p[i];
    return r;
}

// fragment-order index (in f16 units): hp[t][KT][q][b][0]
__device__ __forceinline__ size_t hpi(int t, int KT, int q, int b) {
    return ((((size_t)t * 50 + KT) * 4 + q) * 32 + b) * 8;
}

// ===========================================================================
// rnn0: layer 0. 100 blocks/dir, 8 units/block, 8 waves. 27 k-tiles strided
// kt = w + 8*i (i<4). kt<2: x (cached, packed); 2<=kt<27: h1 prev (bypass).
// ===========================================================================
__global__ __launch_bounds__(512, 1) void rnn0_kernel(
    const f16* __restrict__ xp, f16* __restrict__ h1,
    const float* __restrict__ Wih_f0, const float* __restrict__ Whh_f0, const float* __restrict__ b_f0,
    const float* __restrict__ Wih_b0, const float* __restrict__ Whh_b0, const float* __restrict__ b_b0)
{
    __shared__ float gbuf[8][32][34];
    __shared__ f16  hbuf[256];

    const int tid  = threadIdx.x;
    const int w    = tid >> 6;          // 0..7
    const int lane = tid & 63;
    const int l15  = lane & 15;
    const int quad = lane >> 4;
    const int dir  = blockIdx.x / 100;
    const int blk  = blockIdx.x % 100;
    const int j0   = blk * 8;
    const int jl   = tid >> 5;          // epilogue: hidden unit (tid<256 -> 0..7)
    const int bb   = tid & 31;          // epilogue: batch

    const float* Wih = dir ? Wih_b0 : Wih_f0;
    const float* Whh = dir ? Whh_b0 : Whh_f0;
    const float* bs  = dir ? b_b0  : b_f0;

    // A-fragments: rows gate-major (r>>3 = gate, r&7 = unit), k strided by wave
    half8 afr[2][4];
#pragma unroll
    for (int mt = 0; mt < 2; ++mt) {
        const int r = mt * 16 + l15;
        const int grow = (r >> 3) * HH + j0 + (r & 7);
#pragma unroll
        for (int i = 0; i < 4; ++i) {
            const int kt = w + 8 * i;
            half8 v;
#pragma unroll
            for (int jj = 0; jj < 8; ++jj) v[jj] = (f16)0.f;
            if (kt < 27) {
                if (kt < 2) {
#pragma unroll
                    for (int jj = 0; jj < 8; ++jj) {
                        const int k = kt * 32 + quad * 8 + jj;
                        if (k < DIN) v[jj] = (f16)Wih[(size_t)grow * DIN + k];
                    }
                } else {
                    v = cvt8(Whh + (size_t)grow * HH + (kt - 2) * 32 + quad * 8);
                }
            }
            afr[mt][i] = v;
        }
    }
    const float bi = bs[0 * HH + j0 + jl], bf = bs[1 * HH + j0 + jl],
                bg = bs[2 * HH + j0 + jl], bo = bs[3 * HH + j0 + jl];

    const int KT0 = dir * 25 + (blk >> 2);
    const int q0  = blk & 3;

    // phase-A prefetch registers (x tile, waves 0,1 only)
    half8 px0, px1;
    {
        const int t0 = dir ? (TT - 1) : 0;
        if (w < 2) {
            const f16* p = xp + ((((size_t)t0 * 2 + w) * 4 + quad) * 32) * 8;
            px0 = *(const half8*)(p + (size_t)l15 * 8);
            px1 = *(const half8*)(p + (size_t)(16 + l15) * 8);
        }
    }

    float creg = 0.0f;
    for (int s = 0; s < TT; ++s) {
        const int t  = dir ? (TT - 1 - s) : s;
        const int tp = dir ? t + 1 : t - 1;
        const int tn = dir ? (t > 0 ? t - 1 : 0) : (t < TT - 1 ? t + 1 : t);

        // ---- (1) early prefetch of bypass tiles (hides LLC RTT) ----
        U64H8 rb[4][2];
        if (s > 0) {
#pragma unroll
            for (int i = 0; i < 4; ++i) {
                const int kt = w + 8 * i;
                if (kt >= 2 && kt < 27) {
                    const f16* p = h1 + hpi(tp, dir * 25 + (kt - 2), quad, 0);
                    rb[i][0].u[0] = ald8(p + (size_t)l15 * 8);
                    rb[i][0].u[1] = ald8(p + (size_t)l15 * 8 + 4);
                    rb[i][1].u[0] = ald8(p + (size_t)(16 + l15) * 8);
                    rb[i][1].u[1] = ald8(p + (size_t)(16 + l15) * 8 + 4);
                }
            }
        }

        floatx4 acc[2][2];
        acc[0][0] = (floatx4)0.f; acc[0][1] = (floatx4)0.f;
        acc[1][0] = (floatx4)0.f; acc[1][1] = (floatx4)0.f;

        // ---- (2) phase A: x tile MFMA from prefetched regs (waves 0,1) ----
        if (w < 2) {
            acc[0][0] = __builtin_amdgcn_mfma_f32_16x16x32_f16(afr[0][0], px0, acc[0][0], 0, 0, 0);
            acc[0][1] = __builtin_amdgcn_mfma_f32_16x16x32_f16(afr[0][0], px1, acc[0][1], 0, 0, 0);
            acc[1][0] = __builtin_amdgcn_mfma_f32_16x16x32_f16(afr[1][0], px0, acc[1][0], 0, 0, 0);
            acc[1][1] = __builtin_amdgcn_mfma_f32_16x16x32_f16(afr[1][0], px1, acc[1][1], 0, 0, 0);
            // ---- (3) reload px for next step (completes under phase-B wait)
            const f16* p = xp + ((((size_t)tn * 2 + w) * 4 + quad) * 32) * 8;
            px0 = *(const half8*)(p + (size_t)l15 * 8);
            px1 = *(const half8*)(p + (size_t)(16 + l15) * 8);
        }

        // ---- (4) phase B: bulk verify + bulk respin ----
        if (s > 0) {
            int dm = 0;
#pragma unroll
            for (int i = 0; i < 4; ++i) {
                const int kt = w + 8 * i;
                if (kt >= 2 && kt < 27) {
                    const int bad = (rb[i][0].u[0] == SENT) | (rb[i][0].u[1] == SENT) |
                                    (rb[i][1].u[0] == SENT) | (rb[i][1].u[1] == SENT);
                    dm |= bad << i;
                }
            }
            while (__any(dm != 0)) {
#pragma unroll
                for (int i = 0; i < 4; ++i) {
                    const int kt = w + 8 * i;
                    if (kt >= 2 && kt < 27) {
                        if (dm & (1 << i)) {
                            const f16* p = h1 + hpi(tp, dir * 25 + (kt - 2), quad, 0);
                            rb[i][0].u[0] = ald8(p + (size_t)l15 * 8);
                            rb[i][0].u[1] = ald8(p + (size_t)l15 * 8 + 4);
                            rb[i][1].u[0] = ald8(p + (size_t)(16 + l15) * 8);
                            rb[i][1].u[1] = ald8(p + (size_t)(16 + l15) * 8 + 4);
                        }
                    }
                }
                int nm = 0;
#pragma unroll
                for (int i = 0; i < 4; ++i) {
                    const int kt = w + 8 * i;
                    if (kt >= 2 && kt < 27) {
                        if (dm & (1 << i)) {
                            const int bad = (rb[i][0].u[0] == SENT) | (rb[i][0].u[1] == SENT) |
                                            (rb[i][1].u[0] == SENT) | (rb[i][1].u[1] == SENT);
                            nm |= bad << i;
                        }
                    }
                }
                dm = nm;
            }
            // ---- (5) phase B MFMA ----
#pragma unroll
            for (int i = 0; i < 4; ++i) {
                const int kt = w + 8 * i;
                if (kt >= 2 && kt < 27) {
                    acc[0][0] = __builtin_amdgcn_mfma_f32_16x16x32_f16(afr[0][i], rb[i][0].h, acc[0][0], 0, 0, 0);
                    acc[0][1] = __builtin_amdgcn_mfma_f32_16x16x32_f16(afr[0][i], rb[i][1].h, acc[0][1], 0, 0, 0);
                    acc[1][0] = __builtin_amdgcn_mfma_f32_16x16x32_f16(afr[1][i], rb[i][0].h, acc[1][0], 0, 0, 0);
                    acc[1][1] = __builtin_amdgcn_mfma_f32_16x16x32_f16(afr[1][i], rb[i][1].h, acc[1][1], 0, 0, 0);
                }
            }
        }

        // ---- (6) cross-wave reduce + epilogue ----
#pragma unroll
        for (int mt = 0; mt < 2; ++mt)
#pragma unroll
            for (int nt = 0; nt < 2; ++nt)
#pragma unroll
                for (int rg = 0; rg < 4; ++rg)
                    gbuf[w][mt * 16 + quad * 4 + rg][nt * 16 + l15] = acc[mt][nt][rg];
        __syncthreads();
        if (tid < 256) {
            float gi_ = bi, gf_ = bf, gc_ = bg, go_ = bo;
#pragma unroll
            for (int ww = 0; ww < 8; ++ww) {
                gi_ += gbuf[ww][jl][bb];
                gf_ += gbuf[ww][8 + jl][bb];
                gc_ += gbuf[ww][16 + jl][bb];
                go_ += gbuf[ww][24 + jl][bb];
            }
            const float cn = sigm(gf_) * creg + sigm(gi_) * tanhf(gc_);
            creg = cn;
            hbuf[bb * 8 + jl] = (f16)(sigm(go_) * tanhf(cn));
        }
        __syncthreads();
        if (tid < BB) {
            f16* dst = h1 + hpi(t, KT0, q0, tid);
            const unsigned long long* src = (const unsigned long long*)(hbuf + tid * 8);
            ast8(dst, src[0]);
            ast8(dst + 4, src[1]);
        }
    }
}

// ===========================================================================
// rnn1: layer 1. 100 blocks/dir, 8 units/block, 8 waves. 75 k-tiles strided
// kt = w + 8*i. kt<50 (i<7): h1[t] (cached); 50<=kt<75 (i in 6..9): h2 prev.
// ===========================================================================
__global__ __launch_bounds__(512, 1) void rnn1_kernel(
    const f16* __restrict__ h1, f16* __restrict__ h2,
    const float* __restrict__ Wih_f1, const float* __restrict__ Whh_f1, const float* __restrict__ b_f1,
    const float* __restrict__ Wih_b1, const float* __restrict__ Whh_b1, const float* __restrict__ b_b1)
{
    __shared__ float gbuf[8][32][34];
    __shared__ f16  hbuf[256];

    const int tid  = threadIdx.x;
    const int w    = tid >> 6;
    const int lane = tid & 63;
    const int l15  = lane & 15;
    const int quad = lane >> 4;
    const int dir  = blockIdx.x / 100;
    const int blk  = blockIdx.x % 100;
    const int j0   = blk * 8;
    const int jl   = tid >> 5;
    const int bb   = tid & 31;

    const float* Wih = dir ? Wih_b1 : Wih_f1;
    const float* Whh = dir ? Whh_b1 : Whh_f1;
    const float* bs  = dir ? b_b1  : b_f1;

    half8 afr[2][10];
#pragma unroll
    for (int mt = 0; mt < 2; ++mt) {
        const int r = mt * 16 + l15;
        const int grow = (r >> 3) * HH + j0 + (r & 7);
#pragma unroll
        for (int i = 0; i < 10; ++i) {
            const int kt = w + 8 * i;
            half8 v;
#pragma unroll
            for (int jj = 0; jj < 8; ++jj) v[jj] = (f16)0.f;
            if (kt < 75) {
                if (kt < 50) v = cvt8(Wih + (size_t)grow * KROW + kt * 32 + quad * 8);
                else         v = cvt8(Whh + (size_t)grow * HH + (kt - 50) * 32 + quad * 8);
            }
            afr[mt][i] = v;
        }
    }
    const float bi = bs[0 * HH + j0 + jl], bf = bs[1 * HH + j0 + jl],
                bg = bs[2 * HH + j0 + jl], bo = bs[3 * HH + j0 + jl];

    const int KT0 = dir * 25 + (blk >> 2);
    const int q0  = blk & 3;

    // phase-A prefetch registers: up to 7 tiles (kt = w+8i < 50)
    half8 pa[7][2];
    {
        const int t0 = dir ? (TT - 1) : 0;
#pragma unroll
        for (int i = 0; i < 7; ++i) {
            const int kt = w + 8 * i;
            if (kt < 50) {
                const f16* p = h1 + hpi(t0, kt, quad, 0);
                pa[i][0] = *(const half8*)(p + (size_t)l15 * 8);
                pa[i][1] = *(const half8*)(p + (size_t)(16 + l15) * 8);
            }
        }
    }

    float creg = 0.0f;
    for (int s = 0; s < TT; ++s) {
        const int t  = dir ? (TT - 1 - s) : s;
        const int tp = dir ? t + 1 : t - 1;
        const int tn = dir ? (t > 0 ? t - 1 : 0) : (t < TT - 1 ? t + 1 : t);

        // ---- (1) early prefetch of bypass tiles ----
        U64H8 rb[4][2];
        if (s > 0) {
#pragma unroll
            for (int i = 6; i < 10; ++i) {
                const int kt = w + 8 * i;
                if (kt >= 50 && kt < 75) {
                    const f16* p = h2 + hpi(tp, dir * 25 + (kt - 50), quad, 0);
                    rb[i - 6][0].u[0] = ald8(p + (size_t)l15 * 8);
                    rb[i - 6][0].u[1] = ald8(p + (size_t)l15 * 8 + 4);
                    rb[i - 6][1].u[0] = ald8(p + (size_t)(16 + l15) * 8);
                    rb[i - 6][1].u[1] = ald8(p + (size_t)(16 + l15) * 8 + 4);
                }
            }
        }

        floatx4 acc[2][2];
        acc[0][0] = (floatx4)0.f; acc[0][1] = (floatx4)0.f;
        acc[1][0] = (floatx4)0.f; acc[1][1] = (floatx4)0.f;

        // ---- (2) phase A: h1[t] MFMA from prefetched regs ----
#pragma unroll
        for (int i = 0; i < 7; ++i) {
            const int kt = w + 8 * i;
            if (kt < 50) {
                acc[0][0] = __builtin_amdgcn_mfma_f32_16x16x32_f16(afr[0][i], pa[i][0], acc[0][0], 0, 0, 0);
                acc[0][1] = __builtin_amdgcn_mfma_f32_16x16x32_f16(afr[0][i], pa[i][1], acc[0][1], 0, 0, 0);
                acc[1][0] = __builtin_amdgcn_mfma_f32_16x16x32_f16(afr[1][i], pa[i][0], acc[1][0], 0, 0, 0);
                acc[1][1] = __builtin_amdgcn_mfma_f32_16x16x32_f16(afr[1][i], pa[i][1], acc[1][1], 0, 0, 0);
            }
        }

        // ---- (3) reload pa for next step (completes under phase-B wait) ----
#pragma unroll
        for (int i = 0; i < 7; ++i) {
            const int kt = w + 8 * i;
            if (kt < 50) {
                const f16* p = h1 + hpi(tn, kt, quad, 0);
                pa[i][0] = *(const half8*)(p + (size_t)l15 * 8);
                pa[i][1] = *(const half8*)(p + (size_t)(16 + l15) * 8);
            }
        }

        // ---- (4) phase B: bulk verify + bulk respin ----
        if (s > 0) {
            int dm = 0;
#pragma unroll
            for (int i = 6; i < 10; ++i) {
                const int kt = w + 8 * i;
                if (kt >= 50 && kt < 75) {
                    const int bad = (rb[i - 6][0].u[0] == SENT) | (rb[i - 6][0].u[1] == SENT) |
                                    (rb[i - 6][1].u[0] == SENT) | (rb[i - 6][1].u[1] == SENT);
                    dm |= bad << (i - 6);
                }
            }
            while (__any(dm != 0)) {
#pragma unroll
                for (int i = 6; i < 10; ++i) {
                    const int kt = w + 8 * i;
                    if (kt >= 50 && kt < 75) {
                        if (dm & (1 << (i - 6))) {
                            const f16* p = h2 + hpi(tp, dir * 25 + (kt - 50), quad, 0);
                            rb[i - 6][0].u[0] = ald8(p + (size_t)l15 * 8);
                            rb[i - 6][0].u[1] = ald8(p + (size_t)l15 * 8 + 4);
                            rb[i - 6][1].u[0] = ald8(p + (size_t)(16 + l15) * 8);
                            rb[i - 6][1].u[1] = ald8(p + (size_t)(16 + l15) * 8 + 4);
                        }
                    }
                }
                int nm = 0;
#pragma unroll
                for (int i = 6; i < 10; ++i) {
                    const int kt = w + 8 * i;
                    if (kt >= 50 && kt < 75) {
                        if (dm & (1 << (i - 6))) {
                            const int bad = (rb[i - 6][0].u[0] == SENT) | (rb[i - 6][0].u[1] == SENT) |
                                            (rb[i - 6][1].u[0] == SENT) | (rb[i - 6][1].u[1] == SENT);
                            nm |= bad << (i - 6);
                        }
                    }
                }
                dm = nm;
            }
            // ---- (5) phase B MFMA ----
#pragma unroll
            for (int i = 6; i < 10; ++i) {
                const int kt = w + 8 * i;
                if (kt >= 50 && kt < 75) {
                    acc[0][0] = __builtin_amdgcn_mfma_f32_16x16x32_f16(afr[0][i], rb[i - 6][0].h, acc[0][0], 0, 0, 0);
                    acc[0][1] = __builtin_amdgcn_mfma_f32_16x16x32_f16(afr[0][i], rb[i - 6][1].h, acc[0][1], 0, 0, 0);
                    acc[1][0] = __builtin_amdgcn_mfma_f32_16x16x32_f16(afr[1][i], rb[i - 6][0].h, acc[1][0], 0, 0, 0);
                    acc[1][1] = __builtin_amdgcn_mfma_f32_16x16x32_f16(afr[1][i], rb[i - 6][1].h, acc[1][1], 0, 0, 0);
                }
            }
        }

        // ---- (6) cross-wave reduce + epilogue ----
#pragma unroll
        for (int mt = 0; mt < 2; ++mt)
#pragma unroll
            for (int nt = 0; nt < 2; ++nt)
#pragma unroll
                for (int rg = 0; rg < 4; ++rg)
                    gbuf[w][mt * 16 + quad * 4 + rg][nt * 16 + l15] = acc[mt][nt][rg];
        __syncthreads();
        if (tid < 256) {
            float gi_ = bi, gf_ = bf, gc_ = bg, go_ = bo;
#pragma unroll
            for (int ww = 0; ww < 8; ++ww) {
                gi_ += gbuf[ww][jl][bb];
                gf_ += gbuf[ww][8 + jl][bb];
                gc_ += gbuf[ww][16 + jl][bb];
                go_ += gbuf[ww][24 + jl][bb];
            }
            const float cn = sigm(gf_) * creg + sigm(gi_) * tanhf(gc_);
            creg = cn;
            hbuf[bb * 8 + jl] = (f16)(sigm(go_) * tanhf(cn));
        }
        __syncthreads();
        if (tid < BB) {
            f16* dst = h2 + hpi(t, KT0, q0, tid);
            const unsigned long long* src = (const unsigned long long*)(hbuf + tid * 8);
            ast8(dst, src[0]);
            ast8(dst + 4, src[1]);
        }
    }
}

// ---------------------------------------------------------------------------
// prep: xp packed f16, sin/cos tables, sentinel-fill h1+h2 (105 MB)
__global__ void prep_kernel(const float* __restrict__ x, const float* __restrict__ alphabet,
                            f16* __restrict__ xp, float* __restrict__ sin_t,
                            float* __restrict__ cos_t, unsigned* __restrict__ hsent) {
    const int gid = blockIdx.x * blockDim.x + threadIdx.x;
    const int nth = gridDim.x * blockDim.x;
    for (int idx = gid; idx < TT * BB * 64; idx += nth) {
        const int tb = idx >> 6;            // t*32+b
        const int i  = idx & 63;
        const int t  = tb >> 5;
        const int b  = tb & 31;
        const size_t di = ((((size_t)t * 2 + (i >> 5)) * 4 + ((i >> 3) & 3)) * 32 + b) * 8 + (i & 7);
        xp[di] = (i < DIN) ? (f16)x[(size_t)tb * DIN + i] : (f16)0.f;
    }
    uint4v* hs4 = (uint4v*)hsent;
    const uint4v sv = {0xFFFFFFFFu, 0xFFFFFFFFu, 0xFFFFFFFFu, 0xFFFFFFFFu};
    const int n4 = (2 * 13107200) / 4;
    for (int idx = gid; idx < n4; idx += nth) hs4[idx] = sv;
    if (gid < 60) { sin_t[gid] = sinf(alphabet[gid]); cos_t[gid] = cosf(alphabet[gid]); }
}

// logits -> softmax -> dihedral angles (h2 packed [t][KT][q][b][8])
__global__ __launch_bounds__(640, 1) void head_kernel(
    const f16* __restrict__ h2, const float* __restrict__ Wl, const float* __restrict__ bl,
    const float* __restrict__ sin_t, const float* __restrict__ cos_t,
    float* __restrict__ angles) {
    __shared__ float pl[20][33];
    __shared__ float mx[32];
    const int t = blockIdx.x;
    const int a = threadIdx.x / 32;
    const int b = threadIdx.x & 31;
    if (a < 20) {
        float acc = bl[a];
        const float* wr = Wl + (size_t)a * KROW;
        const f16*   hr = h2 + (size_t)t * 50 * 4 * 32 * 8;
        for (int k8 = 0; k8 < KROW / 8; ++k8) {
            const half8 hv = *(const half8*)(hr + (((size_t)k8) * 32 + b) * 8);
#pragma unroll
            for (int j = 0; j < 8; ++j) acc = fmaf(wr[k8 * 8 + j], (float)hv[j], acc);
        }
        pl[a][b] = acc;
    }
    __syncthreads();
    if (threadIdx.x < 32) {
        float m = pl[0][threadIdx.x];
        for (int i = 1; i < 20; ++i) m = fmaxf(m, pl[i][threadIdx.x]);
        mx[threadIdx.x] = m;
    }
    __syncthreads();
    if (a < 20) pl[a][b] = expf(pl[a][b] - mx[b]);
    __syncthreads();
    if (threadIdx.x < 96) {
        const int c = threadIdx.x / 32, b2 = threadIdx.x & 31;
        float y = 0.f, xx = 0.f;
        for (int i = 0; i < 20; ++i) {
            const float e = pl[i][b2];
            y  = fmaf(e, sin_t[i * 3 + c], y);
            xx = fmaf(e, cos_t[i * 3 + c], xx);
        }
        angles[((size_t)t * BB + b2) * 3 + c] = atan2f(y, xx);
    }
}

// sequential NeRF coordinate extension, one lane per batch element
__global__ void coords_kernel(const float* __restrict__ angles, float* __restrict__ out) {
    const int b = threadIdx.x;
    if (b >= BB) return;
    const float rs[3]  = {1.458f, 1.525f, 1.33f};
    const float ths[3] = {2.124f, 1.941f, 2.028f};
    float ct[3], st[3];
#pragma unroll
    for (int k = 0; k < 3; ++k) { ct[k] = cosf(ths[k]); st[k] = sinf(ths[k]); }
    float pax = 0.f,     pay = 0.f, paz = 0.f;
    float pbx = 1.458f,  pby = 0.f, pbz = 0.f;
    float pcx = 2.f,     pcy = 1.f, pcz = 0.f;
    for (int n = 0; n < 3 * TT; ++n) {
        const int t = n / 3;
        const int k = n - 3 * t;
        const float phi = angles[((size_t)t * BB + b) * 3 + k];
        float ux = pcx - pbx, uy = pcy - pby, uz = pcz - pbz;
        const float il = rsqrtf(ux * ux + uy * uy + uz * uz);
        const float bcx = ux * il, bcy = uy * il, bcz = uz * il;
        const float wx = pbx - pax, wy = pby - pay, wz = pbz - paz;
        float cx = wy * bcz - wz * bcy, cy = wz * bcx - wx * bcz, cz = wx * bcy - wy * bcx;
        const float iln = rsqrtf(cx * cx + cy * cy + cz * cz);
        const float nx = cx * iln, ny = cy * iln, nz = cz * iln;
        const float mxv = ny * bcz - nz * bcy, myv = nz * bcx - nx * bcz, mzv = nx * bcy - ny * bcx;
        float sp, cp;
        __sincosf(phi, &sp, &cp);
        const float rr = rs[k], cth = ct[k], sth = st[k];
        const float dx = pcx - rr * cth * bcx + rr * sth * (cp * mxv + sp * nx);
        const float dy = pcy - rr * cth * bcy + rr * sth * (cp * myv + sp * ny);
        const float dz = pcz - rr * cth * bcz + rr * sth * (cp * mzv + sp * nz);
        float* o = out + ((size_t)n * BB + b) * 3;
        o[0] = dx; o[1] = dy; o[2] = dz;
        pax = pbx; pay = pby; paz = pbz;
        pbx = pcx; pby = pcy; pbz = pcz;
        pcx = dx;  pcy = dy;  pcz = dz;
    }
}

// ---------------------------------------------------------------------------
extern "C" void kernel_launch(void* const* d_in, const int* in_sizes, int n_in,
                              void* d_out, int out_size, void* d_ws, size_t ws_size,
                              hipStream_t stream) {
    (void)in_sizes; (void)n_in; (void)out_size; (void)ws_size;
    const float* x      = (const float*)d_in[0];
    const float* Wih_f0 = (const float*)d_in[1];
    const float* Whh_f0 = (const float*)d_in[2];
    const float* b_f0   = (const float*)d_in[3];
    const float* Wih_b0 = (const float*)d_in[4];
    const float* Whh_b0 = (const float*)d_in[5];
    const float* b_b0   = (const float*)d_in[6];
    const float* Wih_f1 = (const float*)d_in[7];
    const float* Whh_f1 = (const float*)d_in[8];
    const float* b_f1   = (const float*)d_in[9];
    const float* Wih_b1 = (const float*)d_in[10];
    const float* Whh_b1 = (const float*)d_in[11];
    const float* b_b1   = (const float*)d_in[12];
    const float* Wl     = (const float*)d_in[13];
    const float* bl     = (const float*)d_in[14];
    const float* alphabet = (const float*)d_in[15];

    float* ws = (float*)d_ws;
    f16*   xp     = (f16*)(ws + OFF_XT);
    f16*   h1     = (f16*)(ws + OFF_H1);
    f16*   h2     = (f16*)(ws + OFF_H2);
    float* angles = ws + OFF_ANG;
    float* sin_t  = ws + OFF_SIN;
    float* cos_t  = ws + OFF_COS;

    prep_kernel<<<1024, 256, 0, stream>>>(x, alphabet, xp, sin_t, cos_t, (unsigned*)(ws + OFF_H1));
    rnn0_kernel<<<200, 512, 0, stream>>>(xp, h1,
        Wih_f0, Whh_f0, b_f0, Wih_b0, Whh_b0, b_b0);
    rnn1_kernel<<<200, 512, 0, stream>>>(h1, h2,
        Wih_f1, Whh_f1, b_f1, Wih_b1, Whh_b1, b_b1);
    head_kernel<<<TT, 640, 0, stream>>>(h2, Wl, bl, sin_t, cos_t, angles);
    coords_kernel<<<1, 64, 0, stream>>>(angles, (float*)d_out);
}